// Round 1
// baseline (145062.134 us; speedup 1.0000x reference)
//
#include <hip/hip_runtime.h>
#include <stdint.h>

#define BB 64      // batch
#define SS 1024    // memory length
#define TT 511     // decode steps
#define EE 512     // embedding dim
#define UU 1024    // units (= M here)
#define G4 4096    // 4*U

typedef __bf16 bf16x8 __attribute__((ext_vector_type(8)));
typedef float  f32x4  __attribute__((ext_vector_type(4)));
typedef unsigned short u16x8 __attribute__((ext_vector_type(8)));

// ---------- small helpers ----------
__device__ __forceinline__ float bf2f_lo(unsigned int u) {
    union { unsigned int i; float f; } w; w.i = u << 16; return w.f;
}
__device__ __forceinline__ float bf2f_hi(unsigned int u) {
    union { unsigned int i; float f; } w; w.i = u & 0xFFFF0000u; return w.f;
}
__device__ __forceinline__ unsigned short f2bf(float f) {
    union { float f; unsigned int i; } w; w.f = f;
    return (unsigned short)((w.i + 0x7FFFu + ((w.i >> 16) & 1u)) >> 16);
}
__device__ __forceinline__ float bfu2f(unsigned short u) {
    union { unsigned int i; float f; } w; w.i = ((unsigned int)u) << 16; return w.f;
}
__device__ __forceinline__ float fast_tanh(float x) {
    float e = __expf(2.0f * x);
    return 1.0f - 2.0f / (e + 1.0f);
}
__device__ __forceinline__ float sigmoidf_(float x) {
    return 1.0f / (1.0f + __expf(-x));
}

// fragment-pack index (ushort index) for element (m,k) of an A/B pack with KT k-tiles
// layout: [[m>>4][k>>5] tiles][hl][lane=(m&15)+(((k>>3)&3)<<4)][j=k&7]
__device__ __forceinline__ int frag_slot(int m, int k, int KT, int hl) {
    return ((((m >> 4) * KT + (k >> 5)) * 2 + hl) * 64
            + ((m & 15) + (((k >> 3) & 3) << 4))) * 8 + (k & 7);
}

__device__ __forceinline__ f32x4 mfma16(bf16x8 a, bf16x8 b, f32x4 c) {
    return __builtin_amdgcn_mfma_f32_16x16x32_bf16(a, b, c, 0, 0, 0);
}

// ---------- fp32 -> bf16 copy of memory ----------
__global__ void k_cvt(const float4* __restrict__ src, ushort4* __restrict__ dst, int n4)
{
    int idx = blockIdx.x * 256 + threadIdx.x;
    for (int i = idx; i < n4; i += (int)gridDim.x * 256) {
        float4 f = src[i];
        ushort4 o;
        o.x = f2bf(f.x); o.y = f2bf(f.y); o.z = f2bf(f.z); o.w = f2bf(f.w);
        dst[i] = o;
    }
}

// ---------- VALU GEMM, A[M x 1024] @ W[1024 x 1024]; out bf16 (keys) or fp32 (Wafc) ----------
template<int OUTBF16>
__global__ __launch_bounds__(256) void k_mm1024(const float* __restrict__ A,
                                                const float* __restrict__ W,
                                                unsigned short* __restrict__ obf,
                                                float* __restrict__ of32)
{
    __shared__ __align__(16) float As[32][68];
    __shared__ __align__(16) float Ws[32][72];
    const int tid = threadIdx.x;
    const int tx = tid & 15, ty = tid >> 4;
    const int r0 = blockIdx.y * 64;
    const int c0 = blockIdx.x * 64;
    float acc[4][4] = {};
    const int am = tid >> 2, akq = tid & 3;
    const int wc4 = (tid & 15) * 4, wk0 = tid >> 4;
    for (int k0 = 0; k0 < 1024; k0 += 32) {
        const float* p = A + (size_t)(r0 + am) * 1024 + k0 + 8 * akq;
        float4 x0 = *(const float4*)p;
        float4 x1 = *(const float4*)(p + 4);
        As[8*akq+0][am] = x0.x; As[8*akq+1][am] = x0.y; As[8*akq+2][am] = x0.z; As[8*akq+3][am] = x0.w;
        As[8*akq+4][am] = x1.x; As[8*akq+5][am] = x1.y; As[8*akq+6][am] = x1.z; As[8*akq+7][am] = x1.w;
        #pragma unroll
        for (int j = 0; j < 2; ++j) {
            const int kk = wk0 + 16 * j;
            *(float4*)&Ws[kk][wc4] = *(const float4*)&W[(size_t)(k0 + kk) * 1024 + c0 + wc4];
        }
        __syncthreads();
        #pragma unroll
        for (int kk = 0; kk < 32; ++kk) {
            float4 a4 = *(const float4*)&As[kk][4 * ty];
            float4 w4 = *(const float4*)&Ws[kk][4 * tx];
            const float aa[4] = {a4.x, a4.y, a4.z, a4.w};
            const float ww[4] = {w4.x, w4.y, w4.z, w4.w};
            #pragma unroll
            for (int i = 0; i < 4; ++i)
                #pragma unroll
                for (int j = 0; j < 4; ++j)
                    acc[i][j] += aa[i] * ww[j];
        }
        __syncthreads();
    }
    #pragma unroll
    for (int i = 0; i < 4; ++i)
        #pragma unroll
        for (int j = 0; j < 4; ++j) {
            const size_t o = (size_t)(r0 + 4*ty + i) * 1024 + c0 + 4*tx + j;
            if (OUTBF16) obf[o] = f2bf(acc[i][j]);
            else         of32[o] = acc[i][j];
        }
}

// ---------- one-time: pack weights W[k][n] into hi/lo bf16 MFMA fragment order ----------
// nmode=0: k-split (W1 rows [0,split), W2 rows [split,K)); nmode=1: n-split
__global__ void k_packw(const float* __restrict__ W1, const float* __restrict__ W2,
                        int split, int nmode, int KT, int s1, int s2,
                        unsigned short* __restrict__ dst)
{
    const int gid = blockIdx.x * 256 + threadIdx.x;
    const int lane = gid & 63;
    const int rest = gid >> 6;
    const int kt = rest % KT, nt = rest / KT;
    const int n = nt * 16 + (lane & 15);
    const int k0 = kt * 32 + (((lane >> 4) & 3) << 3);
    u16x8 hi, lo;
    #pragma unroll
    for (int j = 0; j < 8; ++j) {
        const int k = k0 + j;
        float f;
        if (nmode) f = (n < split) ? W1[(size_t)k * s1 + n] : W2[(size_t)k * s2 + (n - split)];
        else       f = (k < split) ? W1[(size_t)k * s1 + n] : W2[(size_t)(k - split) * s2 + n];
        hi[j] = f2bf(f);
        lo[j] = f2bf(f - bfu2f(hi[j]));
    }
    u16x8* d8 = (u16x8*)dst;
    d8[((nt * KT + kt) * 2 + 0) * 64 + lane] = hi;
    d8[((nt * KT + kt) * 2 + 1) * 64 + lane] = lo;
}

// ---------- init: c=enc_c; pack h0=enc_h, attn0=0, emb(t=0) into Az ----------
__global__ void k_init2(const float* __restrict__ enc_h, const float* __restrict__ enc_c,
                        const float* __restrict__ emb, const int* __restrict__ tokens,
                        float* __restrict__ c, unsigned short* __restrict__ Az)
{
    const int idx = blockIdx.x * 256 + threadIdx.x;   // 65536
    const int b = idx >> 10, u = idx & 1023;
    c[idx] = enc_c[idx];
    const float hv = enc_h[idx];
    const unsigned short hh = f2bf(hv);
    const unsigned short hl = f2bf(hv - bfu2f(hh));
    Az[frag_slot(b, 1536 + u, 80, 0)] = hh;
    Az[frag_slot(b, 1536 + u, 80, 1)] = hl;
    Az[frag_slot(b, 512 + u, 80, 0)] = 0;
    Az[frag_slot(b, 512 + u, 80, 1)] = 0;
    if (u < EE) {
        const int tok = tokens[b * TT];
        const float v = emb[(size_t)tok * EE + u];
        const unsigned short eh = f2bf(v);
        Az[frag_slot(b, u, 80, 0)] = eh;
        Az[frag_slot(b, u, 80, 1)] = f2bf(v - bfu2f(eh));
    }
}

// ---------- MFMA GEMM: z = [emb|attn|h] @ [Wk;Wr], K=2560 (KT=80), N=4096, 4-way K-split ----------
__global__ __launch_bounds__(256) void k_mfma_z(const unsigned short* __restrict__ Azp,
                                                const unsigned short* __restrict__ Bpp,
                                                float* __restrict__ zpart)
{
    const int lane = threadIdx.x & 63, w = threadIdx.x >> 6;
    const int nt = blockIdx.x * 4 + w;          // 0..255
    const int g  = blockIdx.y;                  // K-split 0..3
    const bf16x8* A = (const bf16x8*)Azp;
    const bf16x8* B = (const bf16x8*)Bpp;
    f32x4 acc[4] = {{0.f,0.f,0.f,0.f},{0.f,0.f,0.f,0.f},{0.f,0.f,0.f,0.f},{0.f,0.f,0.f,0.f}};
    const int kt0 = g * 20;
    for (int kt = kt0; kt < kt0 + 20; ++kt) {
        const bf16x8 bh = B[((nt * 80 + kt) * 2 + 0) * 64 + lane];
        const bf16x8 bl = B[((nt * 80 + kt) * 2 + 1) * 64 + lane];
        #pragma unroll
        for (int m = 0; m < 4; ++m) {
            const bf16x8 ah = A[((m * 80 + kt) * 2 + 0) * 64 + lane];
            const bf16x8 al = A[((m * 80 + kt) * 2 + 1) * 64 + lane];
            acc[m] = mfma16(al, bh, acc[m]);
            acc[m] = mfma16(ah, bl, acc[m]);
            acc[m] = mfma16(ah, bh, acc[m]);
        }
    }
    float* Z = zpart + (size_t)g * BB * G4;
    const int col = nt * 16 + (lane & 15);
    const int rbase = (lane >> 4) * 4;
    #pragma unroll
    for (int m = 0; m < 4; ++m)
        #pragma unroll
        for (int r = 0; r < 4; ++r)
            Z[(size_t)(m * 16 + rbase + r) * G4 + col] = acc[m][r];
}

// ---------- MFMA GEMM: q = h @ Wq, K=1024 (KT=32), N=1024, direct store ----------
__global__ __launch_bounds__(256) void k_mfma_q(const unsigned short* __restrict__ Aqp,
                                                const unsigned short* __restrict__ Bpp,
                                                float* __restrict__ qbuf)
{
    const int lane = threadIdx.x & 63, w = threadIdx.x >> 6;
    const int nt = blockIdx.x * 4 + w;          // 0..63
    const bf16x8* A = (const bf16x8*)Aqp;
    const bf16x8* B = (const bf16x8*)Bpp;
    f32x4 acc[4] = {{0.f,0.f,0.f,0.f},{0.f,0.f,0.f,0.f},{0.f,0.f,0.f,0.f},{0.f,0.f,0.f,0.f}};
    for (int kt = 0; kt < 32; ++kt) {
        const bf16x8 bh = B[((nt * 32 + kt) * 2 + 0) * 64 + lane];
        const bf16x8 bl = B[((nt * 32 + kt) * 2 + 1) * 64 + lane];
        #pragma unroll
        for (int m = 0; m < 4; ++m) {
            const bf16x8 ah = A[((m * 32 + kt) * 2 + 0) * 64 + lane];
            const bf16x8 al = A[((m * 32 + kt) * 2 + 1) * 64 + lane];
            acc[m] = mfma16(al, bh, acc[m]);
            acc[m] = mfma16(ah, bl, acc[m]);
            acc[m] = mfma16(ah, bh, acc[m]);
        }
    }
    const int col = nt * 16 + (lane & 15);
    const int rbase = (lane >> 4) * 4;
    #pragma unroll
    for (int m = 0; m < 4; ++m)
        #pragma unroll
        for (int r = 0; r < 4; ++r)
            qbuf[(size_t)(m * 16 + rbase + r) * UU + col] = acc[m][r];
}

// ---------- MFMA GEMM: [h|ctx] @ [Wa | Wa@Wfc], K=2048 (KT=64), N=2048 ----------
// cols <1024 -> attn: scatter-pack hi/lo into Az (k=512+n); cols >=1024 -> out + bfc
__global__ __launch_bounds__(256) void k_mfma_comb(const unsigned short* __restrict__ Aap,
                                                   const unsigned short* __restrict__ Bpp,
                                                   unsigned short* __restrict__ Az,
                                                   float* __restrict__ out,
                                                   const float* __restrict__ bfc, int t)
{
    const int lane = threadIdx.x & 63, w = threadIdx.x >> 6;
    const int nt = blockIdx.x * 4 + w;          // 0..127
    const bf16x8* A = (const bf16x8*)Aap;
    const bf16x8* B = (const bf16x8*)Bpp;
    f32x4 acc[4] = {{0.f,0.f,0.f,0.f},{0.f,0.f,0.f,0.f},{0.f,0.f,0.f,0.f},{0.f,0.f,0.f,0.f}};
    for (int kt = 0; kt < 64; ++kt) {
        const bf16x8 bh = B[((nt * 64 + kt) * 2 + 0) * 64 + lane];
        const bf16x8 bl = B[((nt * 64 + kt) * 2 + 1) * 64 + lane];
        #pragma unroll
        for (int m = 0; m < 4; ++m) {
            const bf16x8 ah = A[((m * 64 + kt) * 2 + 0) * 64 + lane];
            const bf16x8 al = A[((m * 64 + kt) * 2 + 1) * 64 + lane];
            acc[m] = mfma16(al, bh, acc[m]);
            acc[m] = mfma16(ah, bl, acc[m]);
            acc[m] = mfma16(ah, bh, acc[m]);
        }
    }
    const int n = nt * 16 + (lane & 15);
    const int rbase = (lane >> 4) * 4;
    if (n < 1024) {
        #pragma unroll
        for (int m = 0; m < 4; ++m)
            #pragma unroll
            for (int r = 0; r < 4; ++r) {
                const int row = m * 16 + rbase + r;
                const float v = acc[m][r];
                const unsigned short hh = f2bf(v);
                Az[frag_slot(row, 512 + n, 80, 0)] = hh;
                Az[frag_slot(row, 512 + n, 80, 1)] = f2bf(v - bfu2f(hh));
            }
    } else {
        const int col = n - 1024;
        const float bias = bfc[col];
        #pragma unroll
        for (int m = 0; m < 4; ++m)
            #pragma unroll
            for (int r = 0; r < 4; ++r) {
                const int row = m * 16 + rbase + r;
                out[((size_t)row * TT + t) * 1024 + col] = acc[m][r] + bias;
            }
    }
}

// ---------- LSTM gates: z = sum(zpart[4]) + bias -> h,c; pack h; zero ctx/denom ----------
__global__ void k_gates2(const float* __restrict__ zpart, const float* __restrict__ bias,
                         float* __restrict__ c, unsigned short* __restrict__ Aq,
                         unsigned short* __restrict__ Aa2, unsigned short* __restrict__ Az,
                         float* __restrict__ ctx, float* __restrict__ denom)
{
    const int idx = blockIdx.x * 256 + threadIdx.x;  // 65536
    const int b = idx >> 10, u = idx & 1023;
    float zi = 0.f, zf = 0.f, zg = 0.f, zo = 0.f;
    #pragma unroll
    for (int p = 0; p < 4; ++p) {
        const float* zp = zpart + ((size_t)p * BB + b) * G4;
        zi += zp[u]; zf += zp[u + 1024]; zg += zp[u + 2048]; zo += zp[u + 3072];
    }
    const float i_ = sigmoidf_(zi + bias[u]);
    const float f_ = sigmoidf_(zf + bias[u + 1024]);
    const float g_ = fast_tanh(zg + bias[u + 2048]);
    const float o_ = sigmoidf_(zo + bias[u + 3072]);
    const float cn = f_ * c[idx] + i_ * g_;
    c[idx] = cn;
    const float hv = o_ * fast_tanh(cn);
    const unsigned short hh = f2bf(hv);
    const unsigned short hl = f2bf(hv - bfu2f(hh));
    Aq [frag_slot(b, u,        32, 0)] = hh;  Aq [frag_slot(b, u,        32, 1)] = hl;
    Aa2[frag_slot(b, u,        64, 0)] = hh;  Aa2[frag_slot(b, u,        64, 1)] = hl;
    Az [frag_slot(b, 1536 + u, 80, 0)] = hh;  Az [frag_slot(b, 1536 + u, 80, 1)] = hl;
    ctx[idx] = 0.f;
    if (idx < BB) denom[idx] = 0.f;
}

// ---------- pack ctx/denom into Aa2; pack emb(t+1) into Az ----------
__global__ void k_packctx(const float* __restrict__ ctx, const float* __restrict__ denom,
                          unsigned short* __restrict__ Aa2,
                          const float* __restrict__ emb, const int* __restrict__ tokens,
                          int tnext, unsigned short* __restrict__ Az)
{
    const int idx = blockIdx.x * 256 + threadIdx.x;   // 65536 + 4096
    if (idx < BB * UU) {
        const int b = idx >> 10, u = idx & 1023;
        const float v = ctx[idx] * (1.0f / denom[b]);
        const unsigned short hh = f2bf(v);
        Aa2[frag_slot(b, 1024 + u, 64, 0)] = hh;
        Aa2[frag_slot(b, 1024 + u, 64, 1)] = f2bf(v - bfu2f(hh));
    } else if (tnext < TT) {
        const int r = idx - BB * UU;          // 0..4095: (mrep,kt,lane)
        const int lane = r & 63;
        const int kt = (r >> 6) & 15;
        const int mrep = r >> 10;
        const int bb = mrep * 16 + (lane & 15);
        const int k0 = kt * 32 + (((lane >> 4) & 3) << 3);
        const int tok = tokens[bb * TT + tnext];
        const float* e = emb + (size_t)tok * EE + k0;
        const float4 x0 = *(const float4*)e;
        const float4 x1 = *(const float4*)(e + 4);
        const float f[8] = {x0.x, x0.y, x0.z, x0.w, x1.x, x1.y, x1.z, x1.w};
        u16x8 hi, lo;
        #pragma unroll
        for (int j = 0; j < 8; ++j) {
            hi[j] = f2bf(f[j]);
            lo[j] = f2bf(f[j] - bfu2f(hi[j]));
        }
        u16x8* A8 = (u16x8*)Az;
        A8[((mrep * 80 + kt) * 2 + 0) * 64 + lane] = hi;
        A8[((mrep * 80 + kt) * 2 + 1) * 64 + lane] = lo;
    }
}

// ---------- fused attention sweep: scores + denom + unnormalized ctx ----------
template<int BF16>
__global__ __launch_bounds__(256) void k_attn(const unsigned short* __restrict__ keys,
        const void* __restrict__ mem, const float* __restrict__ qbuf,
        const float* __restrict__ vvec, float* __restrict__ denom, float* __restrict__ ctx)
{
    __shared__ float qs[1024];
    __shared__ float vs[1024];
    __shared__ float es[64];
    const int tid = threadIdx.x;
    const int bid = blockIdx.x;             // 1024 = 64 b * 16 chunks of 64 s
    const int b = bid >> 4, chunk = bid & 15;
    const int s0 = chunk * 64;
    for (int i = tid; i < UU; i += 256) {
        qs[i] = qbuf[(size_t)b * UU + i];
        vs[i] = vvec[i];
    }
    __syncthreads();
    const int lane = tid & 63;
    const int w = tid >> 6;
    float qv[16], vv[16];
    #pragma unroll
    for (int j = 0; j < 2; ++j)
        #pragma unroll
        for (int i = 0; i < 8; ++i) {
            qv[8*j + i] = qs[8*lane + 512*j + i];
            vv[8*j + i] = vs[8*lane + 512*j + i];
        }
    // phase 1: e-scores for this block's 64 s-rows (16 per wave)
    float wsum = 0.f;
    for (int it = 0; it < 16; ++it) {
        const int sl = w * 16 + it;
        const unsigned short* kp = keys + ((size_t)(b * SS + s0 + sl) << 10);
        float acc = 0.f;
        #pragma unroll
        for (int j = 0; j < 2; ++j) {
            uint4 raw = *(const uint4*)&kp[8*lane + 512*j];
            float kx[8];
            kx[0] = bf2f_lo(raw.x); kx[1] = bf2f_hi(raw.x);
            kx[2] = bf2f_lo(raw.y); kx[3] = bf2f_hi(raw.y);
            kx[4] = bf2f_lo(raw.z); kx[5] = bf2f_hi(raw.z);
            kx[6] = bf2f_lo(raw.w); kx[7] = bf2f_hi(raw.w);
            #pragma unroll
            for (int i = 0; i < 8; ++i)
                acc += vv[8*j + i] * fast_tanh(qv[8*j + i] + kx[i]);
        }
        #pragma unroll
        for (int m = 32; m >= 1; m >>= 1) acc += __shfl_xor(acc, m, 64);
        if (lane == 0) {
            const float e = __expf(acc);
            es[sl] = e;
            wsum += e;
        }
    }
    if (lane == 0) atomicAdd(&denom[b], wsum);
    __syncthreads();
    // phase 2: ctx[b][m] += sum_s e[s] * memory[b][s][m] ; 16B/lane loads
    const int m8 = (tid & 127) * 8;
    const int shalf = tid >> 7;
    float a[8] = {};
    #pragma unroll 8
    for (int i = 0; i < 32; ++i) {
        const int sl = shalf * 32 + i;
        const float wgt = es[sl];
        const size_t base = ((size_t)(b * SS + s0 + sl) << 10) + m8;
        if (BF16) {
            uint4 u = *(const uint4*)((const unsigned short*)mem + base);
            a[0] += wgt * bf2f_lo(u.x); a[1] += wgt * bf2f_hi(u.x);
            a[2] += wgt * bf2f_lo(u.y); a[3] += wgt * bf2f_hi(u.y);
            a[4] += wgt * bf2f_lo(u.z); a[5] += wgt * bf2f_hi(u.z);
            a[6] += wgt * bf2f_lo(u.w); a[7] += wgt * bf2f_hi(u.w);
        } else {
            const float* fp = (const float*)mem + base;
            const float4 f0 = *(const float4*)fp;
            const float4 f1 = *(const float4*)(fp + 4);
            a[0] += wgt * f0.x; a[1] += wgt * f0.y; a[2] += wgt * f0.z; a[3] += wgt * f0.w;
            a[4] += wgt * f1.x; a[5] += wgt * f1.y; a[6] += wgt * f1.z; a[7] += wgt * f1.w;
        }
    }
    float* cp = ctx + (size_t)b * UU + m8;
    #pragma unroll
    for (int j = 0; j < 8; ++j) atomicAdd(cp + j, a[j]);
}

// ---------- host ----------
extern "C" void kernel_launch(void* const* d_in, const int* in_sizes, int n_in,
                              void* d_out, int out_size, void* d_ws, size_t ws_size,
                              hipStream_t stream)
{
    const int*   tokens = (const int*)d_in[0];
    const float* memory = (const float*)d_in[1];
    const float* enc_h  = (const float*)d_in[2];
    const float* enc_c  = (const float*)d_in[3];
    const float* emb    = (const float*)d_in[4];
    const float* Wk     = (const float*)d_in[5];
    const float* Wr     = (const float*)d_in[6];
    const float* bias   = (const float*)d_in[7];
    const float* Wm     = (const float*)d_in[8];
    const float* Wq     = (const float*)d_in[9];
    const float* vvec   = (const float*)d_in[10];
    const float* Wa     = (const float*)d_in[11];
    const float* Wfc    = (const float*)d_in[12];
    const float* bfc    = (const float*)d_in[13];
    float* out = (float*)d_out;

    char* ws = (char*)d_ws;
    size_t off = 0;
    auto take = [&](size_t bytes) -> char* {
        char* p = ws + off;
        off = (off + bytes + 255) & ~(size_t)255;
        return p;
    };
    unsigned short* keys   = (unsigned short*)take((size_t)BB * SS * UU * 2);        // 134 MB
    unsigned short* WkrP   = (unsigned short*)take((size_t)256 * 80 * 2 * 64 * 16);  // 42 MB
    unsigned short* WcombP = (unsigned short*)take((size_t)128 * 64 * 2 * 64 * 16);  // 16.8 MB
    unsigned short* WqP    = (unsigned short*)take((size_t)64  * 32 * 2 * 64 * 16);  // 4.2 MB
    float* wafc  = (float*)take((size_t)2048 * 1024 * 4);                            // 8 MB
    float* zpart = (float*)take((size_t)4 * BB * G4 * 4);                            // 4 MB
    float* qbuf  = (float*)take((size_t)BB * UU * 4);
    float* c     = (float*)take((size_t)BB * UU * 4);
    float* ctx   = (float*)take((size_t)BB * UU * 4);
    float* denom = (float*)take(256);
    unsigned short* Az  = (unsigned short*)take((size_t)4 * 80 * 2 * 64 * 16);
    unsigned short* Aq  = (unsigned short*)take((size_t)4 * 32 * 2 * 64 * 16);
    unsigned short* Aa2 = (unsigned short*)take((size_t)4 * 64 * 2 * 64 * 16);
    const bool planA = (off + (size_t)BB * SS * UU * 2) <= ws_size;
    unsigned short* membf = planA ? (unsigned short*)take((size_t)BB * SS * UU * 2) : nullptr;

    // one-time prep
    k_init2<<<dim3(256), dim3(256), 0, stream>>>(enc_h, enc_c, emb, tokens, c, Az);
    if (planA)
        k_cvt<<<dim3(4096), dim3(256), 0, stream>>>((const float4*)memory, (ushort4*)membf,
                                                    (BB * SS * UU) / 4);
    k_mm1024<1><<<dim3(16, 1024), dim3(256), 0, stream>>>(memory, Wm, keys, nullptr); // keys
    k_mm1024<0><<<dim3(16, 32),   dim3(256), 0, stream>>>(Wa, Wfc, nullptr, wafc);    // Wa@Wfc
    k_packw<<<dim3(5120), dim3(256), 0, stream>>>(Wk, Wr, 1536, 0, 80, 4096, 4096, WkrP);
    k_packw<<<dim3(512),  dim3(256), 0, stream>>>(Wq, Wq, 1 << 30, 0, 32, 1024, 1024, WqP);
    k_packw<<<dim3(2048), dim3(256), 0, stream>>>(Wa, wafc, 1024, 1, 64, 1024, 1024, WcombP);

    for (int t = 0; t < TT; ++t) {
        k_mfma_z<<<dim3(64, 4), dim3(256), 0, stream>>>(Az, WkrP, zpart);
        k_gates2<<<dim3(256), dim3(256), 0, stream>>>(zpart, bias, c, Aq, Aa2, Az, ctx, denom);
        k_mfma_q<<<dim3(16), dim3(256), 0, stream>>>(Aq, WqP, qbuf);
        if (planA)
            k_attn<1><<<dim3(1024), dim3(256), 0, stream>>>(keys, membf, qbuf, vvec, denom, ctx);
        else
            k_attn<0><<<dim3(1024), dim3(256), 0, stream>>>(keys, memory, qbuf, vvec, denom, ctx);
        k_packctx<<<dim3(272), dim3(256), 0, stream>>>(ctx, denom, Aa2, emb, tokens, t + 1, Az);
        k_mfma_comb<<<dim3(32), dim3(256), 0, stream>>>(Aa2, WcombP, Az, out, bfc, t);
    }
}

// Round 2
// 79373.248 us; speedup vs baseline: 1.8276x; 1.8276x over previous
//
#include <hip/hip_runtime.h>
#include <stdint.h>

#define BB 64      // batch
#define SS 1024    // memory length
#define TT 511     // decode steps
#define EE 512     // embedding dim
#define UU 1024    // units (= M here)
#define G4 4096    // 4*U

typedef __bf16 bf16x8 __attribute__((ext_vector_type(8)));
typedef float  f32x4  __attribute__((ext_vector_type(4)));
typedef unsigned short u16x8 __attribute__((ext_vector_type(8)));

// ---------- small helpers ----------
__device__ __forceinline__ float bf2f_lo(unsigned int u) {
    union { unsigned int i; float f; } w; w.i = u << 16; return w.f;
}
__device__ __forceinline__ float bf2f_hi(unsigned int u) {
    union { unsigned int i; float f; } w; w.i = u & 0xFFFF0000u; return w.f;
}
__device__ __forceinline__ unsigned short f2bf(float f) {
    union { float f; unsigned int i; } w; w.f = f;
    return (unsigned short)((w.i + 0x7FFFu + ((w.i >> 16) & 1u)) >> 16);
}
__device__ __forceinline__ float bfu2f(unsigned short u) {
    union { unsigned int i; float f; } w; w.i = ((unsigned int)u) << 16; return w.f;
}
__device__ __forceinline__ float fast_tanh(float x) {
    float e = __expf(2.0f * x);
    return 1.0f - 2.0f / (e + 1.0f);
}
__device__ __forceinline__ float sigmoidf_(float x) {
    return 1.0f / (1.0f + __expf(-x));
}

// fragment-pack index (ushort index) for element (m,k) of an A/B pack with KT k-tiles
// layout: [[m>>4][k>>5] tiles][hl][lane=(m&15)+(((k>>3)&3)<<4)][j=k&7]
__device__ __forceinline__ int frag_slot(int m, int k, int KT, int hl) {
    return ((((m >> 4) * KT + (k >> 5)) * 2 + hl) * 64
            + ((m & 15) + (((k >> 3) & 3) << 4))) * 8 + (k & 7);
}

__device__ __forceinline__ f32x4 mfma16(bf16x8 a, bf16x8 b, f32x4 c) {
    return __builtin_amdgcn_mfma_f32_16x16x32_bf16(a, b, c, 0, 0, 0);
}

// ---------- fp32 -> bf16 copy of memory ----------
__global__ void k_cvt(const float4* __restrict__ src, ushort4* __restrict__ dst, int n4)
{
    int idx = blockIdx.x * 256 + threadIdx.x;
    for (int i = idx; i < n4; i += (int)gridDim.x * 256) {
        float4 f = src[i];
        ushort4 o;
        o.x = f2bf(f.x); o.y = f2bf(f.y); o.z = f2bf(f.z); o.w = f2bf(f.w);
        dst[i] = o;
    }
}

// ---------- VALU GEMM, A[M x 1024] @ W[1024 x 1024]; out bf16 (keys) or fp32 (Wafc) ----------
template<int OUTBF16>
__global__ __launch_bounds__(256) void k_mm1024(const float* __restrict__ A,
                                                const float* __restrict__ W,
                                                unsigned short* __restrict__ obf,
                                                float* __restrict__ of32)
{
    __shared__ __align__(16) float As[32][68];
    __shared__ __align__(16) float Ws[32][72];
    const int tid = threadIdx.x;
    const int tx = tid & 15, ty = tid >> 4;
    const int r0 = blockIdx.y * 64;
    const int c0 = blockIdx.x * 64;
    float acc[4][4] = {};
    const int am = tid >> 2, akq = tid & 3;
    const int wc4 = (tid & 15) * 4, wk0 = tid >> 4;
    for (int k0 = 0; k0 < 1024; k0 += 32) {
        const float* p = A + (size_t)(r0 + am) * 1024 + k0 + 8 * akq;
        float4 x0 = *(const float4*)p;
        float4 x1 = *(const float4*)(p + 4);
        As[8*akq+0][am] = x0.x; As[8*akq+1][am] = x0.y; As[8*akq+2][am] = x0.z; As[8*akq+3][am] = x0.w;
        As[8*akq+4][am] = x1.x; As[8*akq+5][am] = x1.y; As[8*akq+6][am] = x1.z; As[8*akq+7][am] = x1.w;
        #pragma unroll
        for (int j = 0; j < 2; ++j) {
            const int kk = wk0 + 16 * j;
            *(float4*)&Ws[kk][wc4] = *(const float4*)&W[(size_t)(k0 + kk) * 1024 + c0 + wc4];
        }
        __syncthreads();
        #pragma unroll
        for (int kk = 0; kk < 32; ++kk) {
            float4 a4 = *(const float4*)&As[kk][4 * ty];
            float4 w4 = *(const float4*)&Ws[kk][4 * tx];
            const float aa[4] = {a4.x, a4.y, a4.z, a4.w};
            const float ww[4] = {w4.x, w4.y, w4.z, w4.w};
            #pragma unroll
            for (int i = 0; i < 4; ++i)
                #pragma unroll
                for (int j = 0; j < 4; ++j)
                    acc[i][j] += aa[i] * ww[j];
        }
        __syncthreads();
    }
    #pragma unroll
    for (int i = 0; i < 4; ++i)
        #pragma unroll
        for (int j = 0; j < 4; ++j) {
            const size_t o = (size_t)(r0 + 4*ty + i) * 1024 + c0 + 4*tx + j;
            if (OUTBF16) obf[o] = f2bf(acc[i][j]);
            else         of32[o] = acc[i][j];
        }
}

// ---------- one-time: pack weights W[k][n] into hi/lo bf16 MFMA fragment order ----------
// nmode=0: k-split (W1 rows [0,split), W2 rows [split,K)); nmode=1: n-split
__global__ void k_packw(const float* __restrict__ W1, const float* __restrict__ W2,
                        int split, int nmode, int KT, int s1, int s2,
                        unsigned short* __restrict__ dst)
{
    const int gid = blockIdx.x * 256 + threadIdx.x;
    const int lane = gid & 63;
    const int rest = gid >> 6;
    const int kt = rest % KT, nt = rest / KT;
    const int n = nt * 16 + (lane & 15);
    const int k0 = kt * 32 + (((lane >> 4) & 3) << 3);
    u16x8 hi, lo;
    #pragma unroll
    for (int j = 0; j < 8; ++j) {
        const int k = k0 + j;
        float f;
        if (nmode) f = (n < split) ? W1[(size_t)k * s1 + n] : W2[(size_t)k * s2 + (n - split)];
        else       f = (k < split) ? W1[(size_t)k * s1 + n] : W2[(size_t)(k - split) * s2 + n];
        hi[j] = f2bf(f);
        lo[j] = f2bf(f - bfu2f(hi[j]));
    }
    u16x8* d8 = (u16x8*)dst;
    d8[((nt * KT + kt) * 2 + 0) * 64 + lane] = hi;
    d8[((nt * KT + kt) * 2 + 1) * 64 + lane] = lo;
}

// ---------- init: c=enc_c; pack h0=enc_h, attn0=0, emb(t=0) into Az ----------
__global__ void k_init2(const float* __restrict__ enc_h, const float* __restrict__ enc_c,
                        const float* __restrict__ emb, const int* __restrict__ tokens,
                        float* __restrict__ c, unsigned short* __restrict__ Az)
{
    const int idx = blockIdx.x * 256 + threadIdx.x;   // 65536
    const int b = idx >> 10, u = idx & 1023;
    c[idx] = enc_c[idx];
    const float hv = enc_h[idx];
    const unsigned short hh = f2bf(hv);
    const unsigned short hl = f2bf(hv - bfu2f(hh));
    Az[frag_slot(b, 1536 + u, 80, 0)] = hh;
    Az[frag_slot(b, 1536 + u, 80, 1)] = hl;
    Az[frag_slot(b, 512 + u, 80, 0)] = 0;
    Az[frag_slot(b, 512 + u, 80, 1)] = 0;
    if (u < EE) {
        const int tok = tokens[b * TT];
        const float v = emb[(size_t)tok * EE + u];
        const unsigned short eh = f2bf(v);
        Az[frag_slot(b, u, 80, 0)] = eh;
        Az[frag_slot(b, u, 80, 1)] = f2bf(v - bfu2f(eh));
    }
}

// ---------- MFMA GEMM: z = [emb|attn|h] @ [Wk;Wr], K=2560 (KT=80), N=4096 ----------
// grid(256 nt, 4 kgroup) x 4 waves; wave w does 5 kt; in-block LDS reduce -> zpart[g]
__global__ __launch_bounds__(256, 4) void k_mfma_z(const unsigned short* __restrict__ Azp,
                                                   const unsigned short* __restrict__ Bpp,
                                                   float* __restrict__ zpart)
{
    __shared__ float red[4][16][64];
    const int lane = threadIdx.x & 63, w = threadIdx.x >> 6;
    const int nt = blockIdx.x;                  // 0..255
    const int g  = blockIdx.y;                  // 0..3
    const bf16x8* A = (const bf16x8*)Azp;
    const bf16x8* B = (const bf16x8*)Bpp;
    f32x4 acc[4] = {{0.f,0.f,0.f,0.f},{0.f,0.f,0.f,0.f},{0.f,0.f,0.f,0.f},{0.f,0.f,0.f,0.f}};
    const int kt0 = g * 20 + w * 5;
    #pragma unroll
    for (int kk = 0; kk < 5; ++kk) {
        const int kt = kt0 + kk;
        const bf16x8 bh = B[((nt * 80 + kt) * 2 + 0) * 64 + lane];
        const bf16x8 bl = B[((nt * 80 + kt) * 2 + 1) * 64 + lane];
        #pragma unroll
        for (int m = 0; m < 4; ++m) {
            const bf16x8 ah = A[((m * 80 + kt) * 2 + 0) * 64 + lane];
            const bf16x8 al = A[((m * 80 + kt) * 2 + 1) * 64 + lane];
            acc[m] = mfma16(al, bh, acc[m]);
            acc[m] = mfma16(ah, bl, acc[m]);
            acc[m] = mfma16(ah, bh, acc[m]);
        }
    }
    #pragma unroll
    for (int m = 0; m < 4; ++m)
        #pragma unroll
        for (int r = 0; r < 4; ++r)
            red[w][m * 4 + r][lane] = acc[m][r];
    __syncthreads();
    // wave w reduces + writes m-tile m=w
    const int m = w;
    float* Z = zpart + (size_t)g * BB * G4;
    const int col = nt * 16 + (lane & 15);
    const int rbase = (lane >> 4) * 4;
    #pragma unroll
    for (int r = 0; r < 4; ++r) {
        const float s = red[0][m*4+r][lane] + red[1][m*4+r][lane]
                      + red[2][m*4+r][lane] + red[3][m*4+r][lane];
        Z[(size_t)(m * 16 + rbase + r) * G4 + col] = s;
    }
}

// ---------- MFMA GEMM: q = h @ Wq, K=1024 (KT=32), N=1024 ----------
// grid(64 nt, 4 kgroup) x 4 waves; wave w does 2 kt; LDS reduce -> qpart[g]
__global__ __launch_bounds__(256, 4) void k_mfma_q(const unsigned short* __restrict__ Aqp,
                                                   const unsigned short* __restrict__ Bpp,
                                                   float* __restrict__ qpart)
{
    __shared__ float red[4][16][64];
    const int lane = threadIdx.x & 63, w = threadIdx.x >> 6;
    const int nt = blockIdx.x;                  // 0..63
    const int g  = blockIdx.y;                  // 0..3
    const bf16x8* A = (const bf16x8*)Aqp;
    const bf16x8* B = (const bf16x8*)Bpp;
    f32x4 acc[4] = {{0.f,0.f,0.f,0.f},{0.f,0.f,0.f,0.f},{0.f,0.f,0.f,0.f},{0.f,0.f,0.f,0.f}};
    const int kt0 = g * 8 + w * 2;
    #pragma unroll
    for (int kk = 0; kk < 2; ++kk) {
        const int kt = kt0 + kk;
        const bf16x8 bh = B[((nt * 32 + kt) * 2 + 0) * 64 + lane];
        const bf16x8 bl = B[((nt * 32 + kt) * 2 + 1) * 64 + lane];
        #pragma unroll
        for (int m = 0; m < 4; ++m) {
            const bf16x8 ah = A[((m * 32 + kt) * 2 + 0) * 64 + lane];
            const bf16x8 al = A[((m * 32 + kt) * 2 + 1) * 64 + lane];
            acc[m] = mfma16(al, bh, acc[m]);
            acc[m] = mfma16(ah, bl, acc[m]);
            acc[m] = mfma16(ah, bh, acc[m]);
        }
    }
    #pragma unroll
    for (int m = 0; m < 4; ++m)
        #pragma unroll
        for (int r = 0; r < 4; ++r)
            red[w][m * 4 + r][lane] = acc[m][r];
    __syncthreads();
    const int m = w;
    float* Q = qpart + (size_t)g * BB * UU;
    const int col = nt * 16 + (lane & 15);
    const int rbase = (lane >> 4) * 4;
    #pragma unroll
    for (int r = 0; r < 4; ++r) {
        const float s = red[0][m*4+r][lane] + red[1][m*4+r][lane]
                      + red[2][m*4+r][lane] + red[3][m*4+r][lane];
        Q[(size_t)(m * 16 + rbase + r) * UU + col] = s;
    }
}

// ---------- MFMA GEMM: [h|ctx] @ [Wa | Wa@Wfc], K=2048 (KT=64), N=2048 ----------
// grid(128 nt) x 8 waves; wave w does 8 kt; LDS reduce; epilogue in-block
// cols <1024 -> attn: scatter-pack hi/lo into Az (k=512+n); cols >=1024 -> out + bfc
__global__ __launch_bounds__(512, 2) void k_mfma_comb(const unsigned short* __restrict__ Aap,
                                                      const unsigned short* __restrict__ Bpp,
                                                      unsigned short* __restrict__ Az,
                                                      float* __restrict__ out,
                                                      const float* __restrict__ bfc, int t)
{
    __shared__ float red[8][16][64];
    const int lane = threadIdx.x & 63, w = threadIdx.x >> 6;   // w 0..7
    const int nt = blockIdx.x;                  // 0..127
    const bf16x8* A = (const bf16x8*)Aap;
    const bf16x8* B = (const bf16x8*)Bpp;
    f32x4 acc[4] = {{0.f,0.f,0.f,0.f},{0.f,0.f,0.f,0.f},{0.f,0.f,0.f,0.f},{0.f,0.f,0.f,0.f}};
    const int kt0 = w * 8;
    #pragma unroll
    for (int kk = 0; kk < 8; ++kk) {
        const int kt = kt0 + kk;
        const bf16x8 bh = B[((nt * 64 + kt) * 2 + 0) * 64 + lane];
        const bf16x8 bl = B[((nt * 64 + kt) * 2 + 1) * 64 + lane];
        #pragma unroll
        for (int m = 0; m < 4; ++m) {
            const bf16x8 ah = A[((m * 64 + kt) * 2 + 0) * 64 + lane];
            const bf16x8 al = A[((m * 64 + kt) * 2 + 1) * 64 + lane];
            acc[m] = mfma16(al, bh, acc[m]);
            acc[m] = mfma16(ah, bl, acc[m]);
            acc[m] = mfma16(ah, bh, acc[m]);
        }
    }
    #pragma unroll
    for (int m = 0; m < 4; ++m)
        #pragma unroll
        for (int r = 0; r < 4; ++r)
            red[w][m * 4 + r][lane] = acc[m][r];
    __syncthreads();
    if (w >= 4) return;
    const int m = w;
    const int n = nt * 16 + (lane & 15);
    const int rbase = (lane >> 4) * 4;
    #pragma unroll
    for (int r = 0; r < 4; ++r) {
        float s = 0.f;
        #pragma unroll
        for (int ww = 0; ww < 8; ++ww) s += red[ww][m*4+r][lane];
        const int row = m * 16 + rbase + r;
        if (n < 1024) {
            const unsigned short hh = f2bf(s);
            Az[frag_slot(row, 512 + n, 80, 0)] = hh;
            Az[frag_slot(row, 512 + n, 80, 1)] = f2bf(s - bfu2f(hh));
        } else {
            const int col = n - 1024;
            out[((size_t)row * TT + t) * 1024 + col] = s + bfc[col];
        }
    }
}

// ---------- LSTM gates: z = sum(zpart[4]) + bias -> h,c; pack h; zero ctx/denom ----------
__global__ void k_gates2(const float* __restrict__ zpart, const float* __restrict__ bias,
                         float* __restrict__ c, unsigned short* __restrict__ Aq,
                         unsigned short* __restrict__ Aa2, unsigned short* __restrict__ Az,
                         float* __restrict__ ctx, float* __restrict__ denom)
{
    const int idx = blockIdx.x * 256 + threadIdx.x;  // 65536
    const int b = idx >> 10, u = idx & 1023;
    float zi = 0.f, zf = 0.f, zg = 0.f, zo = 0.f;
    #pragma unroll
    for (int p = 0; p < 4; ++p) {
        const float* zp = zpart + ((size_t)p * BB + b) * G4;
        zi += zp[u]; zf += zp[u + 1024]; zg += zp[u + 2048]; zo += zp[u + 3072];
    }
    const float i_ = sigmoidf_(zi + bias[u]);
    const float f_ = sigmoidf_(zf + bias[u + 1024]);
    const float g_ = fast_tanh(zg + bias[u + 2048]);
    const float o_ = sigmoidf_(zo + bias[u + 3072]);
    const float cn = f_ * c[idx] + i_ * g_;
    c[idx] = cn;
    const float hv = o_ * fast_tanh(cn);
    const unsigned short hh = f2bf(hv);
    const unsigned short hl = f2bf(hv - bfu2f(hh));
    Aq [frag_slot(b, u,        32, 0)] = hh;  Aq [frag_slot(b, u,        32, 1)] = hl;
    Aa2[frag_slot(b, u,        64, 0)] = hh;  Aa2[frag_slot(b, u,        64, 1)] = hl;
    Az [frag_slot(b, 1536 + u, 80, 0)] = hh;  Az [frag_slot(b, 1536 + u, 80, 1)] = hl;
    ctx[idx] = 0.f;
    if (idx < BB) denom[idx] = 0.f;
}

// ---------- pack ctx/denom into Aa2; pack emb(t+1) into Az ----------
__global__ void k_packctx(const float* __restrict__ ctx, const float* __restrict__ denom,
                          unsigned short* __restrict__ Aa2,
                          const float* __restrict__ emb, const int* __restrict__ tokens,
                          int tnext, unsigned short* __restrict__ Az)
{
    const int idx = blockIdx.x * 256 + threadIdx.x;   // 65536 + 4096
    if (idx < BB * UU) {
        const int b = idx >> 10, u = idx & 1023;
        const float v = ctx[idx] * (1.0f / denom[b]);
        const unsigned short hh = f2bf(v);
        Aa2[frag_slot(b, 1024 + u, 64, 0)] = hh;
        Aa2[frag_slot(b, 1024 + u, 64, 1)] = f2bf(v - bfu2f(hh));
    } else if (tnext < TT) {
        const int r = idx - BB * UU;          // 0..4095: (mrep,kt,lane)
        const int lane = r & 63;
        const int kt = (r >> 6) & 15;
        const int mrep = r >> 10;
        const int bb = mrep * 16 + (lane & 15);
        const int k0 = kt * 32 + (((lane >> 4) & 3) << 3);
        const int tok = tokens[bb * TT + tnext];
        const float* e = emb + (size_t)tok * EE + k0;
        const float4 x0 = *(const float4*)e;
        const float4 x1 = *(const float4*)(e + 4);
        const float f[8] = {x0.x, x0.y, x0.z, x0.w, x1.x, x1.y, x1.z, x1.w};
        u16x8 hi, lo;
        #pragma unroll
        for (int j = 0; j < 8; ++j) {
            hi[j] = f2bf(f[j]);
            lo[j] = f2bf(f[j] - bfu2f(hi[j]));
        }
        u16x8* A8 = (u16x8*)Az;
        A8[((mrep * 80 + kt) * 2 + 0) * 64 + lane] = hi;
        A8[((mrep * 80 + kt) * 2 + 1) * 64 + lane] = lo;
    }
}

// ---------- fused attention sweep: scores + denom + unnormalized ctx ----------
template<int BF16>
__global__ __launch_bounds__(256) void k_attn(const unsigned short* __restrict__ keys,
        const void* __restrict__ mem, const float* __restrict__ qpart,
        const float* __restrict__ vvec, float* __restrict__ denom, float* __restrict__ ctx)
{
    __shared__ float qs[1024];
    __shared__ float vs[1024];
    __shared__ float es[64];
    const int tid = threadIdx.x;
    const int bid = blockIdx.x;             // 1024 = 64 b * 16 chunks of 64 s
    const int b = bid >> 4, chunk = bid & 15;
    const int s0 = chunk * 64;
    for (int i = tid; i < UU; i += 256) {
        const size_t o = (size_t)b * UU + i;
        qs[i] = qpart[o] + qpart[o + (size_t)BB * UU]
              + qpart[o + 2 * (size_t)BB * UU] + qpart[o + 3 * (size_t)BB * UU];
        vs[i] = vvec[i];
    }
    __syncthreads();
    const int lane = tid & 63;
    const int w = tid >> 6;
    float qv[16], vv[16];
    #pragma unroll
    for (int j = 0; j < 2; ++j)
        #pragma unroll
        for (int i = 0; i < 8; ++i) {
            qv[8*j + i] = qs[8*lane + 512*j + i];
            vv[8*j + i] = vs[8*lane + 512*j + i];
        }
    // phase 1: e-scores for this block's 64 s-rows (16 per wave)
    float wsum = 0.f;
    for (int it = 0; it < 16; ++it) {
        const int sl = w * 16 + it;
        const unsigned short* kp = keys + ((size_t)(b * SS + s0 + sl) << 10);
        float acc = 0.f;
        #pragma unroll
        for (int j = 0; j < 2; ++j) {
            uint4 raw = *(const uint4*)&kp[8*lane + 512*j];
            float kx[8];
            kx[0] = bf2f_lo(raw.x); kx[1] = bf2f_hi(raw.x);
            kx[2] = bf2f_lo(raw.y); kx[3] = bf2f_hi(raw.y);
            kx[4] = bf2f_lo(raw.z); kx[5] = bf2f_hi(raw.z);
            kx[6] = bf2f_lo(raw.w); kx[7] = bf2f_hi(raw.w);
            #pragma unroll
            for (int i = 0; i < 8; ++i)
                acc += vv[8*j + i] * fast_tanh(qv[8*j + i] + kx[i]);
        }
        #pragma unroll
        for (int m = 32; m >= 1; m >>= 1) acc += __shfl_xor(acc, m, 64);
        if (lane == 0) {
            const float e = __expf(acc);
            es[sl] = e;
            wsum += e;
        }
    }
    if (lane == 0) atomicAdd(&denom[b], wsum);
    __syncthreads();
    // phase 2: ctx[b][m] += sum_s e[s] * memory[b][s][m] ; 16B/lane loads
    const int m8 = (tid & 127) * 8;
    const int shalf = tid >> 7;
    float a[8] = {};
    #pragma unroll 8
    for (int i = 0; i < 32; ++i) {
        const int sl = shalf * 32 + i;
        const float wgt = es[sl];
        const size_t base = ((size_t)(b * SS + s0 + sl) << 10) + m8;
        if (BF16) {
            uint4 u = *(const uint4*)((const unsigned short*)mem + base);
            a[0] += wgt * bf2f_lo(u.x); a[1] += wgt * bf2f_hi(u.x);
            a[2] += wgt * bf2f_lo(u.y); a[3] += wgt * bf2f_hi(u.y);
            a[4] += wgt * bf2f_lo(u.z); a[5] += wgt * bf2f_hi(u.z);
            a[6] += wgt * bf2f_lo(u.w); a[7] += wgt * bf2f_hi(u.w);
        } else {
            const float* fp = (const float*)mem + base;
            const float4 f0 = *(const float4*)fp;
            const float4 f1 = *(const float4*)(fp + 4);
            a[0] += wgt * f0.x; a[1] += wgt * f0.y; a[2] += wgt * f0.z; a[3] += wgt * f0.w;
            a[4] += wgt * f1.x; a[5] += wgt * f1.y; a[6] += wgt * f1.z; a[7] += wgt * f1.w;
        }
    }
    float* cp = ctx + (size_t)b * UU + m8;
    #pragma unroll
    for (int j = 0; j < 8; ++j) atomicAdd(cp + j, a[j]);
}

// ---------- host ----------
extern "C" void kernel_launch(void* const* d_in, const int* in_sizes, int n_in,
                              void* d_out, int out_size, void* d_ws, size_t ws_size,
                              hipStream_t stream)
{
    const int*   tokens = (const int*)d_in[0];
    const float* memory = (const float*)d_in[1];
    const float* enc_h  = (const float*)d_in[2];
    const float* enc_c  = (const float*)d_in[3];
    const float* emb    = (const float*)d_in[4];
    const float* Wk     = (const float*)d_in[5];
    const float* Wr     = (const float*)d_in[6];
    const float* bias   = (const float*)d_in[7];
    const float* Wm     = (const float*)d_in[8];
    const float* Wq     = (const float*)d_in[9];
    const float* vvec   = (const float*)d_in[10];
    const float* Wa     = (const float*)d_in[11];
    const float* Wfc    = (const float*)d_in[12];
    const float* bfc    = (const float*)d_in[13];
    float* out = (float*)d_out;

    char* ws = (char*)d_ws;
    size_t off = 0;
    auto take = [&](size_t bytes) -> char* {
        char* p = ws + off;
        off = (off + bytes + 255) & ~(size_t)255;
        return p;
    };
    unsigned short* keys   = (unsigned short*)take((size_t)BB * SS * UU * 2);        // 134 MB
    unsigned short* WkrP   = (unsigned short*)take((size_t)256 * 80 * 2 * 64 * 16);  // 42 MB
    unsigned short* WcombP = (unsigned short*)take((size_t)128 * 64 * 2 * 64 * 16);  // 16.8 MB
    unsigned short* WqP    = (unsigned short*)take((size_t)64  * 32 * 2 * 64 * 16);  // 4.2 MB
    float* wafc  = (float*)take((size_t)2048 * 1024 * 4);                            // 8 MB
    float* zpart = (float*)take((size_t)4 * BB * G4 * 4);                            // 4 MB
    float* qpart = (float*)take((size_t)4 * BB * UU * 4);                            // 1 MB
    float* c     = (float*)take((size_t)BB * UU * 4);
    float* ctx   = (float*)take((size_t)BB * UU * 4);
    float* denom = (float*)take(256);
    unsigned short* Az  = (unsigned short*)take((size_t)4 * 80 * 2 * 64 * 16);
    unsigned short* Aq  = (unsigned short*)take((size_t)4 * 32 * 2 * 64 * 16);
    unsigned short* Aa2 = (unsigned short*)take((size_t)4 * 64 * 2 * 64 * 16);
    const bool planA = (off + (size_t)BB * SS * UU * 2) <= ws_size;
    unsigned short* membf = planA ? (unsigned short*)take((size_t)BB * SS * UU * 2) : nullptr;

    // one-time prep
    k_init2<<<dim3(256), dim3(256), 0, stream>>>(enc_h, enc_c, emb, tokens, c, Az);
    if (planA)
        k_cvt<<<dim3(4096), dim3(256), 0, stream>>>((const float4*)memory, (ushort4*)membf,
                                                    (BB * SS * UU) / 4);
    k_mm1024<1><<<dim3(16, 1024), dim3(256), 0, stream>>>(memory, Wm, keys, nullptr); // keys
    k_mm1024<0><<<dim3(16, 32),   dim3(256), 0, stream>>>(Wa, Wfc, nullptr, wafc);    // Wa@Wfc
    k_packw<<<dim3(5120), dim3(256), 0, stream>>>(Wk, Wr, 1536, 0, 80, 4096, 4096, WkrP);
    k_packw<<<dim3(512),  dim3(256), 0, stream>>>(Wq, Wq, 1 << 30, 0, 32, 1024, 1024, WqP);
    k_packw<<<dim3(2048), dim3(256), 0, stream>>>(Wa, wafc, 1024, 1, 64, 1024, 1024, WcombP);

    for (int t = 0; t < TT; ++t) {
        k_mfma_z<<<dim3(256, 4), dim3(256), 0, stream>>>(Az, WkrP, zpart);
        k_gates2<<<dim3(256), dim3(256), 0, stream>>>(zpart, bias, c, Aq, Aa2, Az, ctx, denom);
        k_mfma_q<<<dim3(64, 4), dim3(256), 0, stream>>>(Aq, WqP, qpart);
        if (planA)
            k_attn<1><<<dim3(1024), dim3(256), 0, stream>>>(keys, membf, qpart, vvec, denom, ctx);
        else
            k_attn<0><<<dim3(1024), dim3(256), 0, stream>>>(keys, memory, qpart, vvec, denom, ctx);
        k_packctx<<<dim3(272), dim3(256), 0, stream>>>(ctx, denom, Aa2, emb, tokens, t + 1, Az);
        k_mfma_comb<<<dim3(128), dim3(512), 0, stream>>>(Aa2, WcombP, Az, out, bfc, t);
    }
}

// Round 3
// 53417.578 us; speedup vs baseline: 2.7156x; 1.4859x over previous
//
#include <hip/hip_runtime.h>
#include <stdint.h>

#define BB 64      // batch
#define SS 1024    // memory length
#define TT 511     // decode steps
#define EE 512     // embedding dim
#define UU 1024    // units (= M here)
#define G4 4096    // 4*U

typedef __bf16 bf16x8 __attribute__((ext_vector_type(8)));
typedef float  f32x4  __attribute__((ext_vector_type(4)));
typedef unsigned short u16x8 __attribute__((ext_vector_type(8)));

// ---------- small helpers ----------
__device__ __forceinline__ float bf2f_lo(unsigned int u) {
    union { unsigned int i; float f; } w; w.i = u << 16; return w.f;
}
__device__ __forceinline__ float bf2f_hi(unsigned int u) {
    union { unsigned int i; float f; } w; w.i = u & 0xFFFF0000u; return w.f;
}
__device__ __forceinline__ unsigned short f2bf(float f) {
    union { float f; unsigned int i; } w; w.f = f;
    return (unsigned short)((w.i + 0x7FFFu + ((w.i >> 16) & 1u)) >> 16);
}
__device__ __forceinline__ float bfu2f(unsigned short u) {
    union { unsigned int i; float f; } w; w.i = ((unsigned int)u) << 16; return w.f;
}
__device__ __forceinline__ float fast_tanh(float x) {
    float e = __expf(2.0f * x);
    return 1.0f - 2.0f / (e + 1.0f);
}
__device__ __forceinline__ float sigmoidf_(float x) {
    return 1.0f / (1.0f + __expf(-x));
}

// fragment-pack index (ushort index) for element (m,k) of an A/B pack with KT k-tiles
// layout: [[m>>4][k>>5] tiles][hl][lane=(m&15)+(((k>>3)&3)<<4)][j=k&7]
__device__ __forceinline__ int frag_slot(int m, int k, int KT, int hl) {
    return ((((m >> 4) * KT + (k >> 5)) * 2 + hl) * 64
            + ((m & 15) + (((k >> 3) & 3) << 4))) * 8 + (k & 7);
}

__device__ __forceinline__ f32x4 mfma16(bf16x8 a, bf16x8 b, f32x4 c) {
    return __builtin_amdgcn_mfma_f32_16x16x32_bf16(a, b, c, 0, 0, 0);
}

// ---------- fp32 -> bf16 copy of memory ----------
__global__ void k_cvt(const float4* __restrict__ src, ushort4* __restrict__ dst, int n4)
{
    int idx = blockIdx.x * 256 + threadIdx.x;
    for (int i = idx; i < n4; i += (int)gridDim.x * 256) {
        float4 f = src[i];
        ushort4 o;
        o.x = f2bf(f.x); o.y = f2bf(f.y); o.z = f2bf(f.z); o.w = f2bf(f.w);
        dst[i] = o;
    }
}

// ---------- VALU GEMM, A[M x 1024] @ W[1024 x 1024]; out bf16 (keys) or fp32 (Wafc) ----------
template<int OUTBF16>
__global__ __launch_bounds__(256) void k_mm1024(const float* __restrict__ A,
                                                const float* __restrict__ W,
                                                unsigned short* __restrict__ obf,
                                                float* __restrict__ of32)
{
    __shared__ __align__(16) float As[32][68];
    __shared__ __align__(16) float Ws[32][72];
    const int tid = threadIdx.x;
    const int tx = tid & 15, ty = tid >> 4;
    const int r0 = blockIdx.y * 64;
    const int c0 = blockIdx.x * 64;
    float acc[4][4] = {};
    const int am = tid >> 2, akq = tid & 3;
    const int wc4 = (tid & 15) * 4, wk0 = tid >> 4;
    for (int k0 = 0; k0 < 1024; k0 += 32) {
        const float* p = A + (size_t)(r0 + am) * 1024 + k0 + 8 * akq;
        float4 x0 = *(const float4*)p;
        float4 x1 = *(const float4*)(p + 4);
        As[8*akq+0][am] = x0.x; As[8*akq+1][am] = x0.y; As[8*akq+2][am] = x0.z; As[8*akq+3][am] = x0.w;
        As[8*akq+4][am] = x1.x; As[8*akq+5][am] = x1.y; As[8*akq+6][am] = x1.z; As[8*akq+7][am] = x1.w;
        #pragma unroll
        for (int j = 0; j < 2; ++j) {
            const int kk = wk0 + 16 * j;
            *(float4*)&Ws[kk][wc4] = *(const float4*)&W[(size_t)(k0 + kk) * 1024 + c0 + wc4];
        }
        __syncthreads();
        #pragma unroll
        for (int kk = 0; kk < 32; ++kk) {
            float4 a4 = *(const float4*)&As[kk][4 * ty];
            float4 w4 = *(const float4*)&Ws[kk][4 * tx];
            const float aa[4] = {a4.x, a4.y, a4.z, a4.w};
            const float ww[4] = {w4.x, w4.y, w4.z, w4.w};
            #pragma unroll
            for (int i = 0; i < 4; ++i)
                #pragma unroll
                for (int j = 0; j < 4; ++j)
                    acc[i][j] += aa[i] * ww[j];
        }
        __syncthreads();
    }
    #pragma unroll
    for (int i = 0; i < 4; ++i)
        #pragma unroll
        for (int j = 0; j < 4; ++j) {
            const size_t o = (size_t)(r0 + 4*ty + i) * 1024 + c0 + 4*tx + j;
            if (OUTBF16) obf[o] = f2bf(acc[i][j]);
            else         of32[o] = acc[i][j];
        }
}

// ---------- one-time: pack weights W[k][n] into hi/lo bf16 MFMA fragment order ----------
// nmode=0: k-split (W1 rows [0,split), W2 rows [split,K)); nmode=1: n-split
__global__ void k_packw(const float* __restrict__ W1, const float* __restrict__ W2,
                        int split, int nmode, int KT, int s1, int s2,
                        unsigned short* __restrict__ dst)
{
    const int gid = blockIdx.x * 256 + threadIdx.x;
    const int lane = gid & 63;
    const int rest = gid >> 6;
    const int kt = rest % KT, nt = rest / KT;
    const int n = nt * 16 + (lane & 15);
    const int k0 = kt * 32 + (((lane >> 4) & 3) << 3);
    u16x8 hi, lo;
    #pragma unroll
    for (int j = 0; j < 8; ++j) {
        const int k = k0 + j;
        float f;
        if (nmode) f = (n < split) ? W1[(size_t)k * s1 + n] : W2[(size_t)k * s2 + (n - split)];
        else       f = (k < split) ? W1[(size_t)k * s1 + n] : W2[(size_t)(k - split) * s2 + n];
        hi[j] = f2bf(f);
        lo[j] = f2bf(f - bfu2f(hi[j]));
    }
    u16x8* d8 = (u16x8*)dst;
    d8[((nt * KT + kt) * 2 + 0) * 64 + lane] = hi;
    d8[((nt * KT + kt) * 2 + 1) * 64 + lane] = lo;
}

// ---------- init: c=enc_c; pack h0=enc_h, attn0=0, emb(t=0) into Az ----------
__global__ void k_init2(const float* __restrict__ enc_h, const float* __restrict__ enc_c,
                        const float* __restrict__ emb, const int* __restrict__ tokens,
                        float* __restrict__ c, unsigned short* __restrict__ Az)
{
    const int idx = blockIdx.x * 256 + threadIdx.x;   // 65536
    const int b = idx >> 10, u = idx & 1023;
    c[idx] = enc_c[idx];
    const float hv = enc_h[idx];
    const unsigned short hh = f2bf(hv);
    const unsigned short hl = f2bf(hv - bfu2f(hh));
    Az[frag_slot(b, 1536 + u, 80, 0)] = hh;
    Az[frag_slot(b, 1536 + u, 80, 1)] = hl;
    Az[frag_slot(b, 512 + u, 80, 0)] = 0;
    Az[frag_slot(b, 512 + u, 80, 1)] = 0;
    if (u < EE) {
        const int tok = tokens[b * TT];
        const float v = emb[(size_t)tok * EE + u];
        const unsigned short eh = f2bf(v);
        Az[frag_slot(b, u, 80, 0)] = eh;
        Az[frag_slot(b, u, 80, 1)] = f2bf(v - bfu2f(eh));
    }
}

// ---------- MFMA GEMM: z = [emb|attn|h] @ [Wk;Wr], K=2560 (KT=80), N=4096 ----------
// grid(256 nt, 4 kgroup) x 4 waves; wave w does 5 kt; in-block LDS reduce -> zpart[g]
__global__ __launch_bounds__(256, 4) void k_mfma_z(const unsigned short* __restrict__ Azp,
                                                   const unsigned short* __restrict__ Bpp,
                                                   float* __restrict__ zpart)
{
    __shared__ float red[4][16][64];
    const int lane = threadIdx.x & 63, w = threadIdx.x >> 6;
    const int nt = blockIdx.x;                  // 0..255
    const int g  = blockIdx.y;                  // 0..3
    const bf16x8* A = (const bf16x8*)Azp;
    const bf16x8* B = (const bf16x8*)Bpp;
    f32x4 acc[4] = {{0.f,0.f,0.f,0.f},{0.f,0.f,0.f,0.f},{0.f,0.f,0.f,0.f},{0.f,0.f,0.f,0.f}};
    const int kt0 = g * 20 + w * 5;
    #pragma unroll
    for (int kk = 0; kk < 5; ++kk) {
        const int kt = kt0 + kk;
        const bf16x8 bh = B[((nt * 80 + kt) * 2 + 0) * 64 + lane];
        const bf16x8 bl = B[((nt * 80 + kt) * 2 + 1) * 64 + lane];
        #pragma unroll
        for (int m = 0; m < 4; ++m) {
            const bf16x8 ah = A[((m * 80 + kt) * 2 + 0) * 64 + lane];
            const bf16x8 al = A[((m * 80 + kt) * 2 + 1) * 64 + lane];
            acc[m] = mfma16(al, bh, acc[m]);
            acc[m] = mfma16(ah, bl, acc[m]);
            acc[m] = mfma16(ah, bh, acc[m]);
        }
    }
    #pragma unroll
    for (int m = 0; m < 4; ++m)
        #pragma unroll
        for (int r = 0; r < 4; ++r)
            red[w][m * 4 + r][lane] = acc[m][r];
    __syncthreads();
    // wave w reduces + writes m-tile m=w
    const int m = w;
    float* Z = zpart + (size_t)g * BB * G4;
    const int col = nt * 16 + (lane & 15);
    const int rbase = (lane >> 4) * 4;
    #pragma unroll
    for (int r = 0; r < 4; ++r) {
        const float s = red[0][m*4+r][lane] + red[1][m*4+r][lane]
                      + red[2][m*4+r][lane] + red[3][m*4+r][lane];
        Z[(size_t)(m * 16 + rbase + r) * G4 + col] = s;
    }
}

// ---------- MFMA GEMM: q = h @ Wq, K=1024 (KT=32), N=1024 ----------
// grid(64 nt, 4 kgroup) x 4 waves; wave w does 2 kt; LDS reduce -> qpart[g]
__global__ __launch_bounds__(256, 4) void k_mfma_q(const unsigned short* __restrict__ Aqp,
                                                   const unsigned short* __restrict__ Bpp,
                                                   float* __restrict__ qpart)
{
    __shared__ float red[4][16][64];
    const int lane = threadIdx.x & 63, w = threadIdx.x >> 6;
    const int nt = blockIdx.x;                  // 0..63
    const int g  = blockIdx.y;                  // 0..3
    const bf16x8* A = (const bf16x8*)Aqp;
    const bf16x8* B = (const bf16x8*)Bpp;
    f32x4 acc[4] = {{0.f,0.f,0.f,0.f},{0.f,0.f,0.f,0.f},{0.f,0.f,0.f,0.f},{0.f,0.f,0.f,0.f}};
    const int kt0 = g * 8 + w * 2;
    #pragma unroll
    for (int kk = 0; kk < 2; ++kk) {
        const int kt = kt0 + kk;
        const bf16x8 bh = B[((nt * 32 + kt) * 2 + 0) * 64 + lane];
        const bf16x8 bl = B[((nt * 32 + kt) * 2 + 1) * 64 + lane];
        #pragma unroll
        for (int m = 0; m < 4; ++m) {
            const bf16x8 ah = A[((m * 32 + kt) * 2 + 0) * 64 + lane];
            const bf16x8 al = A[((m * 32 + kt) * 2 + 1) * 64 + lane];
            acc[m] = mfma16(al, bh, acc[m]);
            acc[m] = mfma16(ah, bl, acc[m]);
            acc[m] = mfma16(ah, bh, acc[m]);
        }
    }
    #pragma unroll
    for (int m = 0; m < 4; ++m)
        #pragma unroll
        for (int r = 0; r < 4; ++r)
            red[w][m * 4 + r][lane] = acc[m][r];
    __syncthreads();
    const int m = w;
    float* Q = qpart + (size_t)g * BB * UU;
    const int col = nt * 16 + (lane & 15);
    const int rbase = (lane >> 4) * 4;
    #pragma unroll
    for (int r = 0; r < 4; ++r) {
        const float s = red[0][m*4+r][lane] + red[1][m*4+r][lane]
                      + red[2][m*4+r][lane] + red[3][m*4+r][lane];
        Q[(size_t)(m * 16 + rbase + r) * UU + col] = s;
    }
}

// ---------- MFMA GEMM: [h|ctx] @ [Wa | Wa@Wfc], K=2048 (KT=64), N=2048 ----------
// grid(128 nt) x 8 waves; wave w does 8 kt; LDS reduce; epilogue in-block
// cols <1024 -> attn: scatter-pack hi/lo into Az (k=512+n); cols >=1024 -> out + bfc
__global__ __launch_bounds__(512, 2) void k_mfma_comb(const unsigned short* __restrict__ Aap,
                                                      const unsigned short* __restrict__ Bpp,
                                                      unsigned short* __restrict__ Az,
                                                      float* __restrict__ out,
                                                      const float* __restrict__ bfc, int t)
{
    __shared__ float red[8][16][64];
    const int lane = threadIdx.x & 63, w = threadIdx.x >> 6;   // w 0..7
    const int nt = blockIdx.x;                  // 0..127
    const bf16x8* A = (const bf16x8*)Aap;
    const bf16x8* B = (const bf16x8*)Bpp;
    f32x4 acc[4] = {{0.f,0.f,0.f,0.f},{0.f,0.f,0.f,0.f},{0.f,0.f,0.f,0.f},{0.f,0.f,0.f,0.f}};
    const int kt0 = w * 8;
    #pragma unroll
    for (int kk = 0; kk < 8; ++kk) {
        const int kt = kt0 + kk;
        const bf16x8 bh = B[((nt * 64 + kt) * 2 + 0) * 64 + lane];
        const bf16x8 bl = B[((nt * 64 + kt) * 2 + 1) * 64 + lane];
        #pragma unroll
        for (int m = 0; m < 4; ++m) {
            const bf16x8 ah = A[((m * 64 + kt) * 2 + 0) * 64 + lane];
            const bf16x8 al = A[((m * 64 + kt) * 2 + 1) * 64 + lane];
            acc[m] = mfma16(al, bh, acc[m]);
            acc[m] = mfma16(ah, bl, acc[m]);
            acc[m] = mfma16(ah, bh, acc[m]);
        }
    }
    #pragma unroll
    for (int m = 0; m < 4; ++m)
        #pragma unroll
        for (int r = 0; r < 4; ++r)
            red[w][m * 4 + r][lane] = acc[m][r];
    __syncthreads();
    if (w >= 4) return;
    const int m = w;
    const int n = nt * 16 + (lane & 15);
    const int rbase = (lane >> 4) * 4;
    #pragma unroll
    for (int r = 0; r < 4; ++r) {
        float s = 0.f;
        #pragma unroll
        for (int ww = 0; ww < 8; ++ww) s += red[ww][m*4+r][lane];
        const int row = m * 16 + rbase + r;
        if (n < 1024) {
            const unsigned short hh = f2bf(s);
            Az[frag_slot(row, 512 + n, 80, 0)] = hh;
            Az[frag_slot(row, 512 + n, 80, 1)] = f2bf(s - bfu2f(hh));
        } else {
            const int col = n - 1024;
            out[((size_t)row * TT + t) * 1024 + col] = s + bfc[col];
        }
    }
}

// ---------- LSTM gates: z = sum(zpart[4]) + bias -> h,c; pack h; pack emb(t+1) ----------
__global__ void k_gates2(const float* __restrict__ zpart, const float* __restrict__ bias,
                         float* __restrict__ c, unsigned short* __restrict__ Aq,
                         unsigned short* __restrict__ Aa2, unsigned short* __restrict__ Az,
                         const float* __restrict__ emb, const int* __restrict__ tokens,
                         int tnext)
{
    const int idx = blockIdx.x * 256 + threadIdx.x;  // 272 blocks: 65536 + 4096
    if (idx < BB * UU) {
        const int b = idx >> 10, u = idx & 1023;
        float zi = 0.f, zf = 0.f, zg = 0.f, zo = 0.f;
        #pragma unroll
        for (int p = 0; p < 4; ++p) {
            const float* zp = zpart + ((size_t)p * BB + b) * G4;
            zi += zp[u]; zf += zp[u + 1024]; zg += zp[u + 2048]; zo += zp[u + 3072];
        }
        const float i_ = sigmoidf_(zi + bias[u]);
        const float f_ = sigmoidf_(zf + bias[u + 1024]);
        const float g_ = fast_tanh(zg + bias[u + 2048]);
        const float o_ = sigmoidf_(zo + bias[u + 3072]);
        const float cn = f_ * c[idx] + i_ * g_;
        c[idx] = cn;
        const float hv = o_ * fast_tanh(cn);
        const unsigned short hh = f2bf(hv);
        const unsigned short hl = f2bf(hv - bfu2f(hh));
        Aq [frag_slot(b, u,        32, 0)] = hh;  Aq [frag_slot(b, u,        32, 1)] = hl;
        Aa2[frag_slot(b, u,        64, 0)] = hh;  Aa2[frag_slot(b, u,        64, 1)] = hl;
        Az [frag_slot(b, 1536 + u, 80, 0)] = hh;  Az [frag_slot(b, 1536 + u, 80, 1)] = hl;
    } else if (tnext < TT) {
        const int r = idx - BB * UU;          // 0..4095: (mrep,kt,lane)
        const int lane = r & 63;
        const int kt = (r >> 6) & 15;
        const int mrep = r >> 10;
        const int bb = mrep * 16 + (lane & 15);
        const int k0 = kt * 32 + (((lane >> 4) & 3) << 3);
        const int tok = tokens[bb * TT + tnext];
        const float* e = emb + (size_t)tok * EE + k0;
        const float4 x0 = *(const float4*)e;
        const float4 x1 = *(const float4*)(e + 4);
        const float f[8] = {x0.x, x0.y, x0.z, x0.w, x1.x, x1.y, x1.z, x1.w};
        u16x8 hi, lo;
        #pragma unroll
        for (int j = 0; j < 8; ++j) {
            hi[j] = f2bf(f[j]);
            lo[j] = f2bf(f[j] - bfu2f(hi[j]));
        }
        u16x8* A8 = (u16x8*)Az;
        A8[((mrep * 80 + kt) * 2 + 0) * 64 + lane] = hi;
        A8[((mrep * 80 + kt) * 2 + 1) * 64 + lane] = lo;
    }
}

// ---------- reduce ctx partials, normalize, pack into Aa2 ----------
__global__ void k_packctx(const float* __restrict__ ctxpart, const float* __restrict__ denompart,
                          unsigned short* __restrict__ Aa2)
{
    __shared__ float rdsh;
    const int idx = blockIdx.x * 256 + threadIdx.x;   // 65536
    const int b = idx >> 10, u = idx & 1023;
    if (threadIdx.x == 0) {
        float d = 0.f;
        #pragma unroll
        for (int ch = 0; ch < 16; ++ch) d += denompart[ch * BB + b];
        rdsh = 1.0f / d;
    }
    float v = 0.f;
    #pragma unroll
    for (int ch = 0; ch < 16; ++ch) v += ctxpart[((size_t)ch * BB + b) * UU + u];
    __syncthreads();
    v *= rdsh;
    const unsigned short hh = f2bf(v);
    Aa2[frag_slot(b, 1024 + u, 64, 0)] = hh;
    Aa2[frag_slot(b, 1024 + u, 64, 1)] = f2bf(v - bfu2f(hh));
}

// ---------- fused attention sweep: scores + denom/ctx partials (no atomics) ----------
template<int BF16>
__global__ __launch_bounds__(256) void k_attn(const unsigned short* __restrict__ keys,
        const void* __restrict__ mem, const float* __restrict__ qpart,
        const float* __restrict__ vvec, float* __restrict__ denompart,
        float* __restrict__ ctxpart)
{
    __shared__ float qs[1024];
    __shared__ float vs[1024];
    __shared__ float es[64];
    __shared__ float dsum[4];
    __shared__ __align__(16) float cred[128][8];
    const int tid = threadIdx.x;
    const int bid = blockIdx.x;             // 1024 = 64 b * 16 chunks of 64 s
    const int b = bid >> 4, chunk = bid & 15;
    const int s0 = chunk * 64;
    for (int i = tid; i < UU; i += 256) {
        const size_t o = (size_t)b * UU + i;
        qs[i] = qpart[o] + qpart[o + (size_t)BB * UU]
              + qpart[o + 2 * (size_t)BB * UU] + qpart[o + 3 * (size_t)BB * UU];
        vs[i] = vvec[i];
    }
    __syncthreads();
    const int lane = tid & 63;
    const int w = tid >> 6;
    float qv[16], vv[16];
    #pragma unroll
    for (int j = 0; j < 2; ++j)
        #pragma unroll
        for (int i = 0; i < 8; ++i) {
            qv[8*j + i] = qs[8*lane + 512*j + i];
            vv[8*j + i] = vs[8*lane + 512*j + i];
        }
    // phase 1: e-scores, 2 rows per iteration (4 loads in flight, 2 reduce chains)
    float wsum = 0.f;
    for (int it = 0; it < 8; ++it) {
        const int sl = w * 16 + it * 2;
        const unsigned short* kp0 = keys + ((size_t)(b * SS + s0 + sl) << 10);
        const unsigned short* kp1 = kp0 + 1024;
        const uint4 r00 = *(const uint4*)&kp0[8*lane];
        const uint4 r01 = *(const uint4*)&kp0[8*lane + 512];
        const uint4 r10 = *(const uint4*)&kp1[8*lane];
        const uint4 r11 = *(const uint4*)&kp1[8*lane + 512];
        float acc0 = 0.f, acc1 = 0.f;
        {
            const uint4 rr[2] = {r00, r01};
            #pragma unroll
            for (int j = 0; j < 2; ++j) {
                float kx[8];
                kx[0] = bf2f_lo(rr[j].x); kx[1] = bf2f_hi(rr[j].x);
                kx[2] = bf2f_lo(rr[j].y); kx[3] = bf2f_hi(rr[j].y);
                kx[4] = bf2f_lo(rr[j].z); kx[5] = bf2f_hi(rr[j].z);
                kx[6] = bf2f_lo(rr[j].w); kx[7] = bf2f_hi(rr[j].w);
                #pragma unroll
                for (int i = 0; i < 8; ++i)
                    acc0 += vv[8*j + i] * fast_tanh(qv[8*j + i] + kx[i]);
            }
        }
        {
            const uint4 rr[2] = {r10, r11};
            #pragma unroll
            for (int j = 0; j < 2; ++j) {
                float kx[8];
                kx[0] = bf2f_lo(rr[j].x); kx[1] = bf2f_hi(rr[j].x);
                kx[2] = bf2f_lo(rr[j].y); kx[3] = bf2f_hi(rr[j].y);
                kx[4] = bf2f_lo(rr[j].z); kx[5] = bf2f_hi(rr[j].z);
                kx[6] = bf2f_lo(rr[j].w); kx[7] = bf2f_hi(rr[j].w);
                #pragma unroll
                for (int i = 0; i < 8; ++i)
                    acc1 += vv[8*j + i] * fast_tanh(qv[8*j + i] + kx[i]);
            }
        }
        #pragma unroll
        for (int m = 32; m >= 1; m >>= 1) {
            acc0 += __shfl_xor(acc0, m, 64);
            acc1 += __shfl_xor(acc1, m, 64);
        }
        if (lane == 0) {
            const float e0 = __expf(acc0);
            const float e1 = __expf(acc1);
            es[sl] = e0;
            es[sl + 1] = e1;
            wsum += e0 + e1;
        }
    }
    if (lane == 0) dsum[w] = wsum;
    __syncthreads();
    if (tid == 0)
        denompart[chunk * BB + b] = dsum[0] + dsum[1] + dsum[2] + dsum[3];
    // phase 2: ctxpart[chunk][b][m] = sum_s e[s] * memory[b][s][m] ; 16B/lane loads
    const int m8 = (tid & 127) * 8;
    const int shalf = tid >> 7;
    float a[8] = {};
    #pragma unroll 8
    for (int i = 0; i < 32; ++i) {
        const int sl = shalf * 32 + i;
        const float wgt = es[sl];
        const size_t base = ((size_t)(b * SS + s0 + sl) << 10) + m8;
        if (BF16) {
            uint4 u = *(const uint4*)((const unsigned short*)mem + base);
            a[0] += wgt * bf2f_lo(u.x); a[1] += wgt * bf2f_hi(u.x);
            a[2] += wgt * bf2f_lo(u.y); a[3] += wgt * bf2f_hi(u.y);
            a[4] += wgt * bf2f_lo(u.z); a[5] += wgt * bf2f_hi(u.z);
            a[6] += wgt * bf2f_lo(u.w); a[7] += wgt * bf2f_hi(u.w);
        } else {
            const float* fp = (const float*)mem + base;
            const float4 f0 = *(const float4*)fp;
            const float4 f1 = *(const float4*)(fp + 4);
            a[0] += wgt * f0.x; a[1] += wgt * f0.y; a[2] += wgt * f0.z; a[3] += wgt * f0.w;
            a[4] += wgt * f1.x; a[5] += wgt * f1.y; a[6] += wgt * f1.z; a[7] += wgt * f1.w;
        }
    }
    if (shalf) {
        #pragma unroll
        for (int j = 0; j < 8; ++j) cred[tid - 128][j] = a[j];
    }
    __syncthreads();
    if (!shalf) {
        float* cp = ctxpart + ((size_t)chunk * BB + b) * UU + m8;
        float4 o0, o1;
        o0.x = a[0] + cred[tid][0]; o0.y = a[1] + cred[tid][1];
        o0.z = a[2] + cred[tid][2]; o0.w = a[3] + cred[tid][3];
        o1.x = a[4] + cred[tid][4]; o1.y = a[5] + cred[tid][5];
        o1.z = a[6] + cred[tid][6]; o1.w = a[7] + cred[tid][7];
        *(float4*)cp = o0;
        *(float4*)(cp + 4) = o1;
    }
}

// ---------- host ----------
extern "C" void kernel_launch(void* const* d_in, const int* in_sizes, int n_in,
                              void* d_out, int out_size, void* d_ws, size_t ws_size,
                              hipStream_t stream)
{
    const int*   tokens = (const int*)d_in[0];
    const float* memory = (const float*)d_in[1];
    const float* enc_h  = (const float*)d_in[2];
    const float* enc_c  = (const float*)d_in[3];
    const float* emb    = (const float*)d_in[4];
    const float* Wk     = (const float*)d_in[5];
    const float* Wr     = (const float*)d_in[6];
    const float* bias   = (const float*)d_in[7];
    const float* Wm     = (const float*)d_in[8];
    const float* Wq     = (const float*)d_in[9];
    const float* vvec   = (const float*)d_in[10];
    const float* Wa     = (const float*)d_in[11];
    const float* Wfc    = (const float*)d_in[12];
    const float* bfc    = (const float*)d_in[13];
    float* out = (float*)d_out;

    char* ws = (char*)d_ws;
    size_t off = 0;
    auto take = [&](size_t bytes) -> char* {
        char* p = ws + off;
        off = (off + bytes + 255) & ~(size_t)255;
        return p;
    };
    unsigned short* keys   = (unsigned short*)take((size_t)BB * SS * UU * 2);        // 134 MB
    unsigned short* WkrP   = (unsigned short*)take((size_t)256 * 80 * 2 * 64 * 16);  // 42 MB
    unsigned short* WcombP = (unsigned short*)take((size_t)128 * 64 * 2 * 64 * 16);  // 16.8 MB
    unsigned short* WqP    = (unsigned short*)take((size_t)64  * 32 * 2 * 64 * 16);  // 4.2 MB
    float* wafc  = (float*)take((size_t)2048 * 1024 * 4);                            // 8 MB
    float* zpart = (float*)take((size_t)4 * BB * G4 * 4);                            // 4 MB
    float* qpart = (float*)take((size_t)4 * BB * UU * 4);                            // 1 MB
    float* c     = (float*)take((size_t)BB * UU * 4);
    float* ctxpart   = (float*)take((size_t)16 * BB * UU * 4);                       // 4 MB
    float* denompart = (float*)take((size_t)16 * BB * 4);
    unsigned short* Az  = (unsigned short*)take((size_t)4 * 80 * 2 * 64 * 16);
    unsigned short* Aq  = (unsigned short*)take((size_t)4 * 32 * 2 * 64 * 16);
    unsigned short* Aa2 = (unsigned short*)take((size_t)4 * 64 * 2 * 64 * 16);
    const bool planA = (off + (size_t)BB * SS * UU * 2) <= ws_size;
    unsigned short* membf = planA ? (unsigned short*)take((size_t)BB * SS * UU * 2) : nullptr;

    // one-time prep
    k_init2<<<dim3(256), dim3(256), 0, stream>>>(enc_h, enc_c, emb, tokens, c, Az);
    if (planA)
        k_cvt<<<dim3(4096), dim3(256), 0, stream>>>((const float4*)memory, (ushort4*)membf,
                                                    (BB * SS * UU) / 4);
    k_mm1024<1><<<dim3(16, 1024), dim3(256), 0, stream>>>(memory, Wm, keys, nullptr); // keys
    k_mm1024<0><<<dim3(16, 32),   dim3(256), 0, stream>>>(Wa, Wfc, nullptr, wafc);    // Wa@Wfc
    k_packw<<<dim3(5120), dim3(256), 0, stream>>>(Wk, Wr, 1536, 0, 80, 4096, 4096, WkrP);
    k_packw<<<dim3(512),  dim3(256), 0, stream>>>(Wq, Wq, 1 << 30, 0, 32, 1024, 1024, WqP);
    k_packw<<<dim3(2048), dim3(256), 0, stream>>>(Wa, wafc, 1024, 1, 64, 1024, 1024, WcombP);

    for (int t = 0; t < TT; ++t) {
        k_mfma_z<<<dim3(256, 4), dim3(256), 0, stream>>>(Az, WkrP, zpart);
        k_gates2<<<dim3(272), dim3(256), 0, stream>>>(zpart, bias, c, Aq, Aa2, Az,
                                                      emb, tokens, t + 1);
        k_mfma_q<<<dim3(64, 4), dim3(256), 0, stream>>>(Aq, WqP, qpart);
        if (planA)
            k_attn<1><<<dim3(1024), dim3(256), 0, stream>>>(keys, membf, qpart, vvec,
                                                            denompart, ctxpart);
        else
            k_attn<0><<<dim3(1024), dim3(256), 0, stream>>>(keys, memory, qpart, vvec,
                                                            denompart, ctxpart);
        k_packctx<<<dim3(256), dim3(256), 0, stream>>>(ctxpart, denompart, Aa2);
        k_mfma_comb<<<dim3(128), dim3(512), 0, stream>>>(Aa2, WcombP, Az, out, bfc, t);
    }
}

// Round 5
// 51633.978 us; speedup vs baseline: 2.8094x; 1.0345x over previous
//
#include <hip/hip_runtime.h>
#include <stdint.h>

#define BB 64      // batch
#define SS 1024    // memory length
#define TT 511     // decode steps
#define EE 512     // embedding dim
#define UU 1024    // units (= M here)
#define G4 4096    // 4*U
#define QZKT 48    // K-tiles for qz GEMM (K=1536)
#define CBKT 64    // K-tiles for comb GEMM (K=2048)

typedef __bf16 bf16x8 __attribute__((ext_vector_type(8)));
typedef float  f32x4  __attribute__((ext_vector_type(4)));
typedef unsigned short u16x8 __attribute__((ext_vector_type(8)));

// ---------- small helpers ----------
__device__ __forceinline__ float bf2f_lo(unsigned int u) {
    union { unsigned int i; float f; } w; w.i = u << 16; return w.f;
}
__device__ __forceinline__ float bf2f_hi(unsigned int u) {
    union { unsigned int i; float f; } w; w.i = u & 0xFFFF0000u; return w.f;
}
__device__ __forceinline__ unsigned short f2bf(float f) {
    union { float f; unsigned int i; } w; w.f = f;
    return (unsigned short)((w.i + 0x7FFFu + ((w.i >> 16) & 1u)) >> 16);
}
__device__ __forceinline__ float bfu2f(unsigned short u) {
    union { unsigned int i; float f; } w; w.i = ((unsigned int)u) << 16; return w.f;
}
__device__ __forceinline__ float fast_tanh(float x) {
    float e = __expf(2.0f * x);
    return 1.0f - 2.0f / (e + 1.0f);
}
__device__ __forceinline__ float sigmoidf_(float x) {
    return 1.0f / (1.0f + __expf(-x));
}

// fragment-pack index (ushort index) for element (m,k) of an A/B pack with KT k-tiles
// layout: [[m>>4][k>>5] tiles][hl][lane=(m&15)+(((k>>3)&3)<<4)][j=k&7]
__device__ __forceinline__ int frag_slot(int m, int k, int KT, int hl) {
    return ((((m >> 4) * KT + (k >> 5)) * 2 + hl) * 64
            + ((m & 15) + (((k >> 3) & 3) << 4))) * 8 + (k & 7);
}

__device__ __forceinline__ f32x4 mfma16(bf16x8 a, bf16x8 b, f32x4 c) {
    return __builtin_amdgcn_mfma_f32_16x16x32_bf16(a, b, c, 0, 0, 0);
}

// ---------- fp32 -> bf16 copy of memory ----------
__global__ void k_cvt(const float4* __restrict__ src, ushort4* __restrict__ dst, int n4)
{
    int idx = blockIdx.x * 256 + threadIdx.x;
    for (int i = idx; i < n4; i += (int)gridDim.x * 256) {
        float4 f = src[i];
        ushort4 o;
        o.x = f2bf(f.x); o.y = f2bf(f.y); o.z = f2bf(f.z); o.w = f2bf(f.w);
        dst[i] = o;
    }
}

// ---------- VALU GEMM, A[M x 1024] @ W[1024 x N]; out bf16 or fp32 ----------
template<int OUTBF16>
__global__ __launch_bounds__(256) void k_mmN(const float* __restrict__ A,
                                             const float* __restrict__ W,
                                             unsigned short* __restrict__ obf,
                                             float* __restrict__ of32, int N)
{
    __shared__ __align__(16) float As[32][68];
    __shared__ __align__(16) float Ws[32][72];
    const int tid = threadIdx.x;
    const int tx = tid & 15, ty = tid >> 4;
    const int r0 = blockIdx.y * 64;
    const int c0 = blockIdx.x * 64;
    float acc[4][4] = {};
    const int am = tid >> 2, akq = tid & 3;
    const int wc4 = (tid & 15) * 4, wk0 = tid >> 4;
    for (int k0 = 0; k0 < 1024; k0 += 32) {
        const float* p = A + (size_t)(r0 + am) * 1024 + k0 + 8 * akq;
        float4 x0 = *(const float4*)p;
        float4 x1 = *(const float4*)(p + 4);
        As[8*akq+0][am] = x0.x; As[8*akq+1][am] = x0.y; As[8*akq+2][am] = x0.z; As[8*akq+3][am] = x0.w;
        As[8*akq+4][am] = x1.x; As[8*akq+5][am] = x1.y; As[8*akq+6][am] = x1.z; As[8*akq+7][am] = x1.w;
        #pragma unroll
        for (int j = 0; j < 2; ++j) {
            const int kk = wk0 + 16 * j;
            *(float4*)&Ws[kk][wc4] = *(const float4*)&W[(size_t)(k0 + kk) * N + c0 + wc4];
        }
        __syncthreads();
        #pragma unroll
        for (int kk = 0; kk < 32; ++kk) {
            float4 a4 = *(const float4*)&As[kk][4 * ty];
            float4 w4 = *(const float4*)&Ws[kk][4 * tx];
            const float aa[4] = {a4.x, a4.y, a4.z, a4.w};
            const float ww[4] = {w4.x, w4.y, w4.z, w4.w};
            #pragma unroll
            for (int i = 0; i < 4; ++i)
                #pragma unroll
                for (int j = 0; j < 4; ++j)
                    acc[i][j] += aa[i] * ww[j];
        }
        __syncthreads();
    }
    #pragma unroll
    for (int i = 0; i < 4; ++i)
        #pragma unroll
        for (int j = 0; j < 4; ++j) {
            const size_t o = (size_t)(r0 + 4*ty + i) * N + c0 + 4*tx + j;
            if (OUTBF16) obf[o] = f2bf(acc[i][j]);
            else         of32[o] = acc[i][j];
        }
}

// ---------- one-time: pack weights W[k][n] into hi/lo bf16 MFMA fragment order ----------
// nmode=0: k-split (W1 rows [0,split), W2 rows [split,K)); nmode=1: n-split
__global__ void k_packw(const float* __restrict__ W1, const float* __restrict__ W2,
                        int split, int nmode, int KT, int s1, int s2,
                        unsigned short* __restrict__ dst)
{
    const int gid = blockIdx.x * 256 + threadIdx.x;
    const int lane = gid & 63;
    const int rest = gid >> 6;
    const int kt = rest % KT, nt = rest / KT;
    const int n = nt * 16 + (lane & 15);
    const int k0 = kt * 32 + (((lane >> 4) & 3) << 3);
    u16x8 hi, lo;
    #pragma unroll
    for (int j = 0; j < 8; ++j) {
        const int k = k0 + j;
        float f;
        if (nmode) f = (n < split) ? W1[(size_t)k * s1 + n] : W2[(size_t)k * s2 + (n - split)];
        else       f = (k < split) ? W1[(size_t)k * s1 + n] : W2[(size_t)(k - split) * s2 + n];
        hi[j] = f2bf(f);
        lo[j] = f2bf(f - bfu2f(hi[j]));
    }
    u16x8* d8 = (u16x8*)dst;
    d8[((nt * KT + kt) * 2 + 0) * 64 + lane] = hi;
    d8[((nt * KT + kt) * 2 + 1) * 64 + lane] = lo;
}

// ---------- one-time: pack B for qz GEMM: K=1536, N=5120 ----------
// n<4096: k<512 -> Wk[k][n], else Wr[k-512][n];  n>=4096: k<512 -> 0, else Wq[k-512][n-4096]
__global__ void k_packqz(const float* __restrict__ Wk, const float* __restrict__ Wr,
                         const float* __restrict__ Wq, unsigned short* __restrict__ dst)
{
    const int gid = blockIdx.x * 256 + threadIdx.x;   // 320*48*64 = 983040
    const int lane = gid & 63;
    const int rest = gid >> 6;
    const int kt = rest % QZKT, nt = rest / QZKT;
    const int n = nt * 16 + (lane & 15);
    const int k0 = kt * 32 + (((lane >> 4) & 3) << 3);
    u16x8 hi, lo;
    #pragma unroll
    for (int j = 0; j < 8; ++j) {
        const int k = k0 + j;
        float f;
        if (n < 4096) f = (k < 512) ? Wk[(size_t)k * 4096 + n] : Wr[(size_t)(k - 512) * 4096 + n];
        else          f = (k < 512) ? 0.f : Wq[(size_t)(k - 512) * 1024 + (n - 4096)];
        hi[j] = f2bf(f);
        lo[j] = f2bf(f - bfu2f(hi[j]));
    }
    u16x8* d8 = (u16x8*)dst;
    d8[((nt * QZKT + kt) * 2 + 0) * 64 + lane] = hi;
    d8[((nt * QZKT + kt) * 2 + 1) * 64 + lane] = lo;
}

// ---------- init: c=enc_c; pack h0=enc_h and emb(t=0) into Aqz; zattn=0 ----------
__global__ void k_init2(const float* __restrict__ enc_h, const float* __restrict__ enc_c,
                        const float* __restrict__ emb, const int* __restrict__ tokens,
                        float* __restrict__ c, unsigned short* __restrict__ Aqz,
                        float* __restrict__ zattn)
{
    const int idx = blockIdx.x * 256 + threadIdx.x;   // 65536
    const int b = idx >> 10, u = idx & 1023;
    c[idx] = enc_c[idx];
    const float hv = enc_h[idx];
    const unsigned short hh = f2bf(hv);
    Aqz[frag_slot(b, 512 + u, QZKT, 0)] = hh;
    Aqz[frag_slot(b, 512 + u, QZKT, 1)] = f2bf(hv - bfu2f(hh));
    if (u < EE) {
        const int tok = tokens[b * TT];
        const float v = emb[(size_t)tok * EE + u];
        const unsigned short eh = f2bf(v);
        Aqz[frag_slot(b, u, QZKT, 0)] = eh;
        Aqz[frag_slot(b, u, QZKT, 1)] = f2bf(v - bfu2f(eh));
    }
    #pragma unroll
    for (int j = 0; j < 4; ++j) zattn[idx + j * 65536] = 0.f;   // 64*4096
}

// ---------- one-time MFMA GEMM: keys = membf(bf16) @ Wm(hi/lo)  -> bf16 keys ----------
// grid(4, 512): 256 cols x 128 rows per block; 4 waves x 2 m-tiles
__global__ __launch_bounds__(256, 2) void k_keys_mfma(const unsigned short* __restrict__ membf,
        const unsigned short* __restrict__ WmP, unsigned short* __restrict__ keys)
{
    __shared__ bf16x8 Bs[32][64];    // 32 KB: frags for one kt (16 nt x hi/lo)
    const int tid = threadIdx.x, lane = tid & 63, w = tid >> 6;
    const int bx = blockIdx.x;       // 0..3   (256-col group)
    const int by = blockIdx.y;       // 0..511 (128-row group)
    const bf16x8* mb = (const bf16x8*)membf;
    const bf16x8* B8 = (const bf16x8*)WmP;
    f32x4 acc[2][16];
    const f32x4 z4 = {0.f, 0.f, 0.f, 0.f};
    #pragma unroll
    for (int i = 0; i < 2; ++i)
        #pragma unroll
        for (int j = 0; j < 16; ++j) acc[i][j] = z4;
    const int r0a = by * 128 + (w * 2) * 16 + (lane & 15);
    const int r0b = r0a + 16;
    const int kq = lane >> 4;        // 0..3
    for (int kt = 0; kt < 32; ++kt) {
        const bf16x8 ah0 = mb[(size_t)r0a * 128 + kt * 4 + kq];
        const bf16x8 ah1 = mb[(size_t)r0b * 128 + kt * 4 + kq];
        __syncthreads();
        #pragma unroll
        for (int j = 0; j < 8; ++j) {
            const int slot = tid + j * 256;
            const int frag = slot >> 6, l2 = slot & 63;
            const int ntl = frag >> 1, hl = frag & 1;
            Bs[frag][l2] = B8[((((size_t)bx * 16 + ntl) * 32 + kt) * 2 + hl) * 64 + l2];
        }
        __syncthreads();
        #pragma unroll
        for (int nt = 0; nt < 16; ++nt) {
            const bf16x8 bh = Bs[nt * 2][lane];
            const bf16x8 bl = Bs[nt * 2 + 1][lane];
            acc[0][nt] = mfma16(ah0, bl, acc[0][nt]);
            acc[0][nt] = mfma16(ah0, bh, acc[0][nt]);
            acc[1][nt] = mfma16(ah1, bl, acc[1][nt]);
            acc[1][nt] = mfma16(ah1, bh, acc[1][nt]);
        }
    }
    const int rbase = (lane >> 4) * 4;
    const int c16 = lane & 15;
    #pragma unroll
    for (int mi = 0; mi < 2; ++mi)
        #pragma unroll
        for (int nt = 0; nt < 16; ++nt)
            #pragma unroll
            for (int r = 0; r < 4; ++r) {
                const int row = by * 128 + (w * 2 + mi) * 16 + rbase + r;
                const int col = bx * 256 + nt * 16 + c16;
                keys[(size_t)row * 1024 + col] = f2bf(acc[mi][nt][r]);
            }
}

// ---------- MFMA GEMM qz: [emb_{t+1}|h] @ [Wk1;Wr | 0;Wq], K=1536, N=5120 ----------
// grid(320 nt, 4 g) x 4 waves; wave w does 3 kt; LDS reduce -> zpart2[g] / qpart[g]
__global__ __launch_bounds__(256, 4) void k_mfma_qz(const unsigned short* __restrict__ Ap,
                                                    const unsigned short* __restrict__ Bp,
                                                    float* __restrict__ zpart2,
                                                    float* __restrict__ qpart)
{
    __shared__ float red[4][16][64];
    const int lane = threadIdx.x & 63, w = threadIdx.x >> 6;
    const int nt = blockIdx.x;                  // 0..319
    const int g  = blockIdx.y;                  // 0..3
    const bf16x8* A = (const bf16x8*)Ap;
    const bf16x8* B = (const bf16x8*)Bp;
    f32x4 acc[4] = {{0.f,0.f,0.f,0.f},{0.f,0.f,0.f,0.f},{0.f,0.f,0.f,0.f},{0.f,0.f,0.f,0.f}};
    const int kt0 = g * 12 + w * 3;
    #pragma unroll
    for (int kk = 0; kk < 3; ++kk) {
        const int kt = kt0 + kk;
        const bf16x8 bh = B[((nt * QZKT + kt) * 2 + 0) * 64 + lane];
        const bf16x8 bl = B[((nt * QZKT + kt) * 2 + 1) * 64 + lane];
        #pragma unroll
        for (int m = 0; m < 4; ++m) {
            const bf16x8 ah = A[((m * QZKT + kt) * 2 + 0) * 64 + lane];
            const bf16x8 al = A[((m * QZKT + kt) * 2 + 1) * 64 + lane];
            acc[m] = mfma16(al, bh, acc[m]);
            acc[m] = mfma16(ah, bl, acc[m]);
            acc[m] = mfma16(ah, bh, acc[m]);
        }
    }
    #pragma unroll
    for (int m = 0; m < 4; ++m)
        #pragma unroll
        for (int r = 0; r < 4; ++r)
            red[w][m * 4 + r][lane] = acc[m][r];
    __syncthreads();
    const int m = w;
    const int c16 = lane & 15;
    const int rbase = (lane >> 4) * 4;
    #pragma unroll
    for (int r = 0; r < 4; ++r) {
        const float s = red[0][m*4+r][lane] + red[1][m*4+r][lane]
                      + red[2][m*4+r][lane] + red[3][m*4+r][lane];
        const int row = m * 16 + rbase + r;
        if (nt < 256) zpart2[(size_t)g * BB * G4 + (size_t)row * G4 + nt * 16 + c16] = s;
        else          qpart [(size_t)g * BB * UU + (size_t)row * UU + (nt - 256) * 16 + c16] = s;
    }
}

// ---------- MFMA GEMM comb: [h|ctx] @ [Wa@Wfc | Wa@Wk2], K=2048, N=5120 ----------
// grid(320 nt) x 8 waves; n<1024 -> out+bfc; n>=1024 -> zattn (for next step's gates)
__global__ __launch_bounds__(512, 2) void k_mfma_comb2(const unsigned short* __restrict__ Ap,
                                                       const unsigned short* __restrict__ Bp,
                                                       float* __restrict__ zattn,
                                                       float* __restrict__ out,
                                                       const float* __restrict__ bfc, int t)
{
    __shared__ float red[8][16][64];
    const int lane = threadIdx.x & 63, w = threadIdx.x >> 6;   // w 0..7
    const int nt = blockIdx.x;                  // 0..319
    const bf16x8* A = (const bf16x8*)Ap;
    const bf16x8* B = (const bf16x8*)Bp;
    f32x4 acc[4] = {{0.f,0.f,0.f,0.f},{0.f,0.f,0.f,0.f},{0.f,0.f,0.f,0.f},{0.f,0.f,0.f,0.f}};
    const int kt0 = w * 8;
    #pragma unroll
    for (int kk = 0; kk < 8; ++kk) {
        const int kt = kt0 + kk;
        const bf16x8 bh = B[((nt * CBKT + kt) * 2 + 0) * 64 + lane];
        const bf16x8 bl = B[((nt * CBKT + kt) * 2 + 1) * 64 + lane];
        #pragma unroll
        for (int m = 0; m < 4; ++m) {
            const bf16x8 ah = A[((m * CBKT + kt) * 2 + 0) * 64 + lane];
            const bf16x8 al = A[((m * CBKT + kt) * 2 + 1) * 64 + lane];
            acc[m] = mfma16(al, bh, acc[m]);
            acc[m] = mfma16(ah, bl, acc[m]);
            acc[m] = mfma16(ah, bh, acc[m]);
        }
    }
    #pragma unroll
    for (int m = 0; m < 4; ++m)
        #pragma unroll
        for (int r = 0; r < 4; ++r)
            red[w][m * 4 + r][lane] = acc[m][r];
    __syncthreads();
    if (w >= 4) return;
    const int m = w;
    const int c16 = lane & 15;
    const int rbase = (lane >> 4) * 4;
    #pragma unroll
    for (int r = 0; r < 4; ++r) {
        float s = 0.f;
        #pragma unroll
        for (int ww = 0; ww < 8; ++ww) s += red[ww][m*4+r][lane];
        const int row = m * 16 + rbase + r;
        if (nt < 64) {
            const int col = nt * 16 + c16;
            out[((size_t)row * TT + t) * 1024 + col] = s + bfc[col];
        } else {
            zattn[(size_t)row * G4 + (nt - 64) * 16 + c16] = s;
        }
    }
}

// ---------- LSTM gates: z = sum(zpart2[4]) + zattn + bias -> h,c; pack h; pack emb(t+1) ----------
__global__ void k_gates3(const float* __restrict__ zpart2, const float* __restrict__ zattn,
                         const float* __restrict__ bias, float* __restrict__ c,
                         unsigned short* __restrict__ Aqz, unsigned short* __restrict__ Acomb,
                         const float* __restrict__ emb, const int* __restrict__ tokens,
                         int tnext)
{
    const int idx = blockIdx.x * 256 + threadIdx.x;  // 272 blocks: 65536 + 4096
    if (idx < BB * UU) {
        const int b = idx >> 10, u = idx & 1023;
        float zi = zattn[(size_t)b * G4 + u];
        float zf = zattn[(size_t)b * G4 + u + 1024];
        float zg = zattn[(size_t)b * G4 + u + 2048];
        float zo = zattn[(size_t)b * G4 + u + 3072];
        #pragma unroll
        for (int p = 0; p < 4; ++p) {
            const float* zp = zpart2 + ((size_t)p * BB + b) * G4;
            zi += zp[u]; zf += zp[u + 1024]; zg += zp[u + 2048]; zo += zp[u + 3072];
        }
        const float i_ = sigmoidf_(zi + bias[u]);
        const float f_ = sigmoidf_(zf + bias[u + 1024]);
        const float g_ = fast_tanh(zg + bias[u + 2048]);
        const float o_ = sigmoidf_(zo + bias[u + 3072]);
        const float cn = f_ * c[idx] + i_ * g_;
        c[idx] = cn;
        const float hv = o_ * fast_tanh(cn);
        const unsigned short hh = f2bf(hv);
        const unsigned short hl = f2bf(hv - bfu2f(hh));
        Aqz  [frag_slot(b, 512 + u, QZKT, 0)] = hh;  Aqz  [frag_slot(b, 512 + u, QZKT, 1)] = hl;
        Acomb[frag_slot(b, u,       CBKT, 0)] = hh;  Acomb[frag_slot(b, u,       CBKT, 1)] = hl;
    } else if (tnext < TT) {
        const int r = idx - BB * UU;          // 0..4095: (mrep,kt,lane)
        const int lane = r & 63;
        const int kt = (r >> 6) & 15;
        const int mrep = r >> 10;
        const int bb = mrep * 16 + (lane & 15);
        const int k0 = kt * 32 + (((lane >> 4) & 3) << 3);
        const int tok = tokens[bb * TT + tnext];
        const float* e = emb + (size_t)tok * EE + k0;
        const float4 x0 = *(const float4*)e;
        const float4 x1 = *(const float4*)(e + 4);
        const float f[8] = {x0.x, x0.y, x0.z, x0.w, x1.x, x1.y, x1.z, x1.w};
        u16x8 hi, lo;
        #pragma unroll
        for (int j = 0; j < 8; ++j) {
            hi[j] = f2bf(f[j]);
            lo[j] = f2bf(f[j] - bfu2f(hi[j]));
        }
        u16x8* A8 = (u16x8*)Aqz;
        A8[((mrep * QZKT + kt) * 2 + 0) * 64 + lane] = hi;
        A8[((mrep * QZKT + kt) * 2 + 1) * 64 + lane] = lo;
    }
}

// ---------- reduce ctx partials, normalize, pack into Acomb (k = 1024+u) ----------
__global__ void k_packctx2(const float* __restrict__ ctxpart, const float* __restrict__ denompart,
                           unsigned short* __restrict__ Acomb)
{
    __shared__ float rdsh;
    const int idx = blockIdx.x * 256 + threadIdx.x;   // 65536
    const int b = idx >> 10, u = idx & 1023;
    if (threadIdx.x == 0) {
        float d = 0.f;
        #pragma unroll
        for (int ch = 0; ch < 16; ++ch) d += denompart[ch * BB + b];
        rdsh = 1.0f / d;
    }
    float v = 0.f;
    #pragma unroll
    for (int ch = 0; ch < 16; ++ch) v += ctxpart[((size_t)ch * BB + b) * UU + u];
    __syncthreads();
    v *= rdsh;
    const unsigned short hh = f2bf(v);
    Acomb[frag_slot(b, 1024 + u, CBKT, 0)] = hh;
    Acomb[frag_slot(b, 1024 + u, CBKT, 1)] = f2bf(v - bfu2f(hh));
}

// ---------- fused attention sweep: scores + denom/ctx partials (no atomics) ----------
template<int BF16>
__global__ __launch_bounds__(256) void k_attn(const unsigned short* __restrict__ keys,
        const void* __restrict__ mem, const float* __restrict__ qpart,
        const float* __restrict__ vvec, float* __restrict__ denompart,
        float* __restrict__ ctxpart)
{
    __shared__ float qs[1024];
    __shared__ float vs[1024];
    __shared__ float es[64];
    __shared__ float dsum[4];
    __shared__ __align__(16) float cred[128][8];
    const int tid = threadIdx.x;
    const int bid = blockIdx.x;             // 1024 = 64 b * 16 chunks of 64 s
    const int b = bid >> 4, chunk = bid & 15;
    const int s0 = chunk * 64;
    for (int i = tid; i < UU; i += 256) {
        const size_t o = (size_t)b * UU + i;
        qs[i] = qpart[o] + qpart[o + (size_t)BB * UU]
              + qpart[o + 2 * (size_t)BB * UU] + qpart[o + 3 * (size_t)BB * UU];
        vs[i] = vvec[i];
    }
    __syncthreads();
    const int lane = tid & 63;
    const int w = tid >> 6;
    float qv[16], vv[16];
    #pragma unroll
    for (int j = 0; j < 2; ++j)
        #pragma unroll
        for (int i = 0; i < 8; ++i) {
            qv[8*j + i] = qs[8*lane + 512*j + i];
            vv[8*j + i] = vs[8*lane + 512*j + i];
        }
    // phase 1: e-scores, 2 rows per iteration (4 loads in flight, 2 reduce chains)
    float wsum = 0.f;
    for (int it = 0; it < 8; ++it) {
        const int sl = w * 16 + it * 2;
        const unsigned short* kp0 = keys + ((size_t)(b * SS + s0 + sl) << 10);
        const unsigned short* kp1 = kp0 + 1024;
        const uint4 r00 = *(const uint4*)&kp0[8*lane];
        const uint4 r01 = *(const uint4*)&kp0[8*lane + 512];
        const uint4 r10 = *(const uint4*)&kp1[8*lane];
        const uint4 r11 = *(const uint4*)&kp1[8*lane + 512];
        float acc0 = 0.f, acc1 = 0.f;
        {
            const uint4 rr[2] = {r00, r01};
            #pragma unroll
            for (int j = 0; j < 2; ++j) {
                float kx[8];
                kx[0] = bf2f_lo(rr[j].x); kx[1] = bf2f_hi(rr[j].x);
                kx[2] = bf2f_lo(rr[j].y); kx[3] = bf2f_hi(rr[j].y);
                kx[4] = bf2f_lo(rr[j].z); kx[5] = bf2f_hi(rr[j].z);
                kx[6] = bf2f_lo(rr[j].w); kx[7] = bf2f_hi(rr[j].w);
                #pragma unroll
                for (int i = 0; i < 8; ++i)
                    acc0 += vv[8*j + i] * fast_tanh(qv[8*j + i] + kx[i]);
            }
        }
        {
            const uint4 rr[2] = {r10, r11};
            #pragma unroll
            for (int j = 0; j < 2; ++j) {
                float kx[8];
                kx[0] = bf2f_lo(rr[j].x); kx[1] = bf2f_hi(rr[j].x);
                kx[2] = bf2f_lo(rr[j].y); kx[3] = bf2f_hi(rr[j].y);
                kx[4] = bf2f_lo(rr[j].z); kx[5] = bf2f_hi(rr[j].z);
                kx[6] = bf2f_lo(rr[j].w); kx[7] = bf2f_hi(rr[j].w);
                #pragma unroll
                for (int i = 0; i < 8; ++i)
                    acc1 += vv[8*j + i] * fast_tanh(qv[8*j + i] + kx[i]);
            }
        }
        #pragma unroll
        for (int m = 32; m >= 1; m >>= 1) {
            acc0 += __shfl_xor(acc0, m, 64);
            acc1 += __shfl_xor(acc1, m, 64);
        }
        if (lane == 0) {
            const float e0 = __expf(acc0);
            const float e1 = __expf(acc1);
            es[sl] = e0;
            es[sl + 1] = e1;
            wsum += e0 + e1;
        }
    }
    if (lane == 0) dsum[w] = wsum;
    __syncthreads();
    if (tid == 0)
        denompart[chunk * BB + b] = dsum[0] + dsum[1] + dsum[2] + dsum[3];
    // phase 2: ctxpart[chunk][b][m] = sum_s e[s] * memory[b][s][m] ; 16B/lane loads
    const int m8 = (tid & 127) * 8;
    const int shalf = tid >> 7;
    float a[8] = {};
    #pragma unroll 8
    for (int i = 0; i < 32; ++i) {
        const int sl = shalf * 32 + i;
        const float wgt = es[sl];
        const size_t base = ((size_t)(b * SS + s0 + sl) << 10) + m8;
        if (BF16) {
            uint4 u = *(const uint4*)((const unsigned short*)mem + base);
            a[0] += wgt * bf2f_lo(u.x); a[1] += wgt * bf2f_hi(u.x);
            a[2] += wgt * bf2f_lo(u.y); a[3] += wgt * bf2f_hi(u.y);
            a[4] += wgt * bf2f_lo(u.z); a[5] += wgt * bf2f_hi(u.z);
            a[6] += wgt * bf2f_lo(u.w); a[7] += wgt * bf2f_hi(u.w);
        } else {
            const float* fp = (const float*)mem + base;
            const float4 f0 = *(const float4*)fp;
            const float4 f1 = *(const float4*)(fp + 4);
            a[0] += wgt * f0.x; a[1] += wgt * f0.y; a[2] += wgt * f0.z; a[3] += wgt * f0.w;
            a[4] += wgt * f1.x; a[5] += wgt * f1.y; a[6] += wgt * f1.z; a[7] += wgt * f1.w;
        }
    }
    if (shalf) {
        #pragma unroll
        for (int j = 0; j < 8; ++j) cred[tid - 128][j] = a[j];
    }
    __syncthreads();
    if (!shalf) {
        float* cp = ctxpart + ((size_t)chunk * BB + b) * UU + m8;
        float4 o0, o1;
        o0.x = a[0] + cred[tid][0]; o0.y = a[1] + cred[tid][1];
        o0.z = a[2] + cred[tid][2]; o0.w = a[3] + cred[tid][3];
        o1.x = a[4] + cred[tid][4]; o1.y = a[5] + cred[tid][5];
        o1.z = a[6] + cred[tid][6]; o1.w = a[7] + cred[tid][7];
        *(float4*)cp = o0;
        *(float4*)(cp + 4) = o1;
    }
}

// ---------- host ----------
extern "C" void kernel_launch(void* const* d_in, const int* in_sizes, int n_in,
                              void* d_out, int out_size, void* d_ws, size_t ws_size,
                              hipStream_t stream)
{
    const int*   tokens = (const int*)d_in[0];
    const float* memory = (const float*)d_in[1];
    const float* enc_h  = (const float*)d_in[2];
    const float* enc_c  = (const float*)d_in[3];
    const float* emb    = (const float*)d_in[4];
    const float* Wk     = (const float*)d_in[5];
    const float* Wr     = (const float*)d_in[6];
    const float* bias   = (const float*)d_in[7];
    const float* Wm     = (const float*)d_in[8];
    const float* Wq     = (const float*)d_in[9];
    const float* vvec   = (const float*)d_in[10];
    const float* Wa     = (const float*)d_in[11];
    const float* Wfc    = (const float*)d_in[12];
    const float* bfc    = (const float*)d_in[13];
    float* out = (float*)d_out;

    char* ws = (char*)d_ws;
    size_t off = 0;
    auto take = [&](size_t bytes) -> char* {
        char* p = ws + off;
        off = (off + bytes + 255) & ~(size_t)255;
        return p;
    };
    unsigned short* keys    = (unsigned short*)take((size_t)BB * SS * UU * 2);        // 134 MB
    unsigned short* WqzP    = (unsigned short*)take((size_t)320 * QZKT * 2 * 64 * 16); // 31.5 MB
    unsigned short* Wcomb2P = (unsigned short*)take((size_t)320 * CBKT * 2 * 64 * 16); // 41.9 MB
    unsigned short* WmP     = (unsigned short*)take((size_t)64 * 32 * 2 * 64 * 16);    // 4.2 MB
    float* zpart2 = (float*)take((size_t)4 * BB * G4 * 4);                             // 4 MB
    float* qpart  = (float*)take((size_t)4 * BB * UU * 4);                             // 1 MB
    float* c      = (float*)take((size_t)BB * UU * 4);
    float* ctxpart   = (float*)take((size_t)16 * BB * UU * 4);                         // 4 MB
    float* denompart = (float*)take((size_t)16 * BB * 4);
    float* zattn  = (float*)take((size_t)BB * G4 * 4);                                 // 1 MB
    unsigned short* Aqz   = (unsigned short*)take((size_t)4 * QZKT * 2 * 64 * 16);     // 393 KB
    unsigned short* Acomb = (unsigned short*)take((size_t)4 * CBKT * 2 * 64 * 16);     // 524 KB
    // scratch region: wafc (8.4 MB) + wk2f (33.6 MB); later overwritten by membf (planA)
    char* scratch = take((size_t)2048 * 1024 * 4 + (size_t)2048 * 4096 * 4);           // 42 MB
    float* wafc = (float*)scratch;
    float* wk2f = (float*)(scratch + (size_t)2048 * 1024 * 4);
    const size_t scratch_off = (size_t)(scratch - ws);
    const bool planA = (scratch_off + (size_t)BB * SS * UU * 2 + 256) <= ws_size;
    unsigned short* membf = planA ? (unsigned short*)scratch : nullptr;

    // ---- one-time prep ----
    k_init2<<<dim3(256), dim3(256), 0, stream>>>(enc_h, enc_c, emb, tokens, c, Aqz, zattn);
    // folded weights (fp32, in scratch): wafc = Wa@Wfc ; wk2f = Wa@Wk[512:1536,:]
    k_mmN<0><<<dim3(16, 32), dim3(256), 0, stream>>>(Wa, Wfc, nullptr, wafc, 1024);
    k_mmN<0><<<dim3(64, 32), dim3(256), 0, stream>>>(Wa, Wk + (size_t)512 * 4096, nullptr, wk2f, 4096);
    // pack B matrices (Wcomb2P consumes scratch BEFORE membf overwrites it)
    k_packw<<<dim3(5120), dim3(256), 0, stream>>>(wafc, wk2f, 1024, 1, CBKT, 1024, 4096, Wcomb2P);
    k_packqz<<<dim3(3840), dim3(256), 0, stream>>>(Wk, Wr, Wq, WqzP);
    if (planA) {
        k_packw<<<dim3(512), dim3(256), 0, stream>>>(Wm, Wm, 1 << 30, 0, 32, 1024, 1024, WmP);
        k_cvt<<<dim3(4096), dim3(256), 0, stream>>>((const float4*)memory, (ushort4*)membf,
                                                    (BB * SS * UU) / 4);
        k_keys_mfma<<<dim3(4, 512), dim3(256), 0, stream>>>(membf, WmP, keys);
    } else {
        k_mmN<1><<<dim3(16, 1024), dim3(256), 0, stream>>>(memory, Wm, keys, nullptr, 1024);
    }
    // prologue: zpre_0 from [emb_0 | enc_h]  (q output is garbage, overwritten in-loop)
    k_mfma_qz<<<dim3(320, 4), dim3(256), 0, stream>>>(Aqz, WqzP, zpart2, qpart);

    for (int t = 0; t < TT; ++t) {
        k_gates3<<<dim3(272), dim3(256), 0, stream>>>(zpart2, zattn, bias, c, Aqz, Acomb,
                                                      emb, tokens, t + 1);
        k_mfma_qz<<<dim3(320, 4), dim3(256), 0, stream>>>(Aqz, WqzP, zpart2, qpart);
        if (planA)
            k_attn<1><<<dim3(1024), dim3(256), 0, stream>>>(keys, membf, qpart, vvec,
                                                            denompart, ctxpart);
        else
            k_attn<0><<<dim3(1024), dim3(256), 0, stream>>>(keys, memory, qpart, vvec,
                                                            denompart, ctxpart);
        k_packctx2<<<dim3(256), dim3(256), 0, stream>>>(ctxpart, denompart, Acomb);
        k_mfma_comb2<<<dim3(320), dim3(512), 0, stream>>>(Acomb, Wcomb2P, zattn, out, bfc, t);
    }
}